// Round 6
// baseline (605.126 us; speedup 1.0000x reference)
//
#include <hip/hip_runtime.h>
#include <cstddef>
#include <cstdint>

#define BS      2
#define SEQ     2048
#define DM      1024
#define NH      16
#define DEPTH   64
#define ROWS    (BS*SEQ)          // 4096
#define BHS     (BS*NH*SEQ)       // 65536

typedef unsigned short u16;
typedef __attribute__((ext_vector_type(8))) short short8v;
typedef __attribute__((ext_vector_type(4))) float f32x4;

// swizzled byte offset into a [64 rows][128 B] LDS tile (T2 / G4 fix)
#define SWZ(row, cb) ((((row) << 7)) | ((cb) ^ (((row) & 7) << 4)))

__device__ __forceinline__ u16 f2bf(float x) {
    unsigned u = __builtin_bit_cast(unsigned, x);
    unsigned r = u + 0x7FFFu + ((u >> 16) & 1u);
    return (u16)(r >> 16);
}
__device__ __forceinline__ float bf2f(u16 h) {
    unsigned u = ((unsigned)h) << 16;
    return __builtin_bit_cast(float, u);
}

// fast csch(x)=1/sinh(x): big path 2t/(t^2-1), t=e^x; small |x|<0.04: 1/x - x/6.
__device__ __forceinline__ float fast_csch(float x) {
    float t    = __expf(x);
    float den  = fmaf(t, t, -1.0f);
    bool  sm   = fabsf(x) < 0.04f;
    float d    = sm ? x : den;
    float r    = __builtin_amdgcn_rcpf(d);
    float big  = 2.0f * t * r;
    float smal = fmaf(x, -(1.0f/6.0f), r);
    return sm ? smal : big;
}

// ---------------------------------------------------------------------------
// 4-in-1 weight transpose + split: W[K][N] fp32 -> [N][K] bf16 hi/lo
// ---------------------------------------------------------------------------
__global__ __launch_bounds__(256) void wsplit4_kernel(
    const float* __restrict__ W0, const float* __restrict__ W1,
    const float* __restrict__ W2_, const float* __restrict__ W3,
    u16* __restrict__ H0, u16* __restrict__ L0, u16* __restrict__ H1, u16* __restrict__ L1,
    u16* __restrict__ H2, u16* __restrict__ L2, u16* __restrict__ H3, u16* __restrict__ L3)
{
    const float* W; u16* H; u16* L;
    switch (blockIdx.z) {
        case 0: W = W0; H = H0; L = L0; break;
        case 1: W = W1; H = H1; L = L1; break;
        case 2: W = W2_; H = H2; L = L2; break;
        default: W = W3; H = H3; L = L3; break;
    }
    __shared__ float tile[32][33];
    const int bn = blockIdx.x, bk = blockIdx.y;
    const int c = threadIdx.x & 31, r0 = threadIdx.x >> 5;
#pragma unroll
    for (int r = 0; r < 32; r += 8)
        tile[r0 + r][c] = W[(size_t)(bk*32 + r0 + r) * DM + bn*32 + c];
    __syncthreads();
#pragma unroll
    for (int r = 0; r < 32; r += 8) {
        float v = tile[c][r0 + r];
        u16 h = f2bf(v);
        size_t o = (size_t)(bn*32 + r0 + r) * DM + bk*32 + c;
        H[o] = h;
        L[o] = f2bf(v - bf2f(h));
    }
}

// ---------------------------------------------------------------------------
// Elementwise split fp32 -> bf16 hi/lo (used for non-transposed Wq copy)
// ---------------------------------------------------------------------------
__global__ __launch_bounds__(256) void split_kernel(
    const float* __restrict__ X, u16* __restrict__ H, u16* __restrict__ L)
{
    int i = blockIdx.x * 256 + threadIdx.x;        // float4 index
    float4 v = ((const float4*)X)[i];
    u16 h0 = f2bf(v.x), h1 = f2bf(v.y), h2 = f2bf(v.z), h3 = f2bf(v.w);
    u16 l0 = f2bf(v.x - bf2f(h0)), l1 = f2bf(v.y - bf2f(h1));
    u16 l2 = f2bf(v.z - bf2f(h2)), l3 = f2bf(v.w - bf2f(h3));
    uint2 hh, ll;
    hh.x = (unsigned)h0 | ((unsigned)h1 << 16); hh.y = (unsigned)h2 | ((unsigned)h3 << 16);
    ll.x = (unsigned)l0 | ((unsigned)l1 << 16); ll.y = (unsigned)l2 | ((unsigned)l3 << 16);
    ((uint2*)H)[i] = hh;
    ((uint2*)L)[i] = ll;
}

// ---------------------------------------------------------------------------
// bq2[n] = bq[n] + sum_k bq[k] * Wq[k][n]   (16 blocks x 256 thr, 4-way k-split)
// ---------------------------------------------------------------------------
__global__ __launch_bounds__(256) void bias2_kernel(
    const float* __restrict__ bq, const float* __restrict__ Wq,
    float* __restrict__ bq2)
{
    __shared__ float part[4][64];
    const int t = threadIdx.x;
    const int nl = t & 63, kk = t >> 6;
    const int n = blockIdx.x * 64 + nl;
    float acc = 0.0f;
#pragma unroll 8
    for (int k = kk*256; k < kk*256 + 256; ++k)
        acc = fmaf(bq[k], Wq[(size_t)k * DM + n], acc);
    part[kk][nl] = acc;
    __syncthreads();
    if (t < 64)
        bq2[blockIdx.x*64 + t] = part[0][t] + part[1][t] + part[2][t] + part[3][t]
                               + bq[blockIdx.x*64 + t];
}

// ---------------------------------------------------------------------------
// Split-bf16 MFMA GEMM: C = A@W (+ bias). A split bf16 [M][K]; B split [N][K].
// Tile 128x64, BK=32, 4 waves. OUT_MODE 0: fp32 C; 1: split Ch/Cl.
// ---------------------------------------------------------------------------
template<int OUT_MODE>
__global__ __launch_bounds__(256) void gemm_mfma(
    const u16* __restrict__ Ah, const u16* __restrict__ Al,
    const u16* __restrict__ Bh, const u16* __restrict__ Bl,
    const float* __restrict__ bias, float* __restrict__ C,
    u16* __restrict__ Ch, u16* __restrict__ Cl)
{
    constexpr int K = 1024, N = 1024;
    __shared__ u16 AsH[128*40], AsL[128*40], BsH[64*40], BsL[64*40];

    const int t = threadIdx.x;
    const int m0 = blockIdx.y * 128;
    const int n0 = blockIdx.x * 64;
    const int lane = t & 63, w = t >> 6;
    const int wr = w >> 1, wc = w & 1;
    const int lr = lane & 15, lk = lane >> 4;

    f32x4 acc[4][2];
#pragma unroll
    for (int i = 0; i < 4; ++i)
#pragma unroll
        for (int j = 0; j < 2; ++j) acc[i][j] = (f32x4){0.f,0.f,0.f,0.f};

    for (int k0 = 0; k0 < K; k0 += 32) {
        __syncthreads();
#pragma unroll
        for (int r = 0; r < 2; ++r) {
            int s = r*256 + t;
            int row = s >> 2, c = s & 3;
            size_t g = (size_t)(m0 + row) * K + k0 + c*8;
            *(short8v*)&AsH[row*40 + c*8] = *(const short8v*)&Ah[g];
            *(short8v*)&AsL[row*40 + c*8] = *(const short8v*)&Al[g];
        }
        {
            int row = t >> 2, c = t & 3;
            size_t g = (size_t)(n0 + row) * K + k0 + c*8;
            *(short8v*)&BsH[row*40 + c*8] = *(const short8v*)&Bh[g];
            *(short8v*)&BsL[row*40 + c*8] = *(const short8v*)&Bl[g];
        }
        __syncthreads();

        short8v ah[4], al[4], bh[2], bl[2];
#pragma unroll
        for (int i = 0; i < 4; ++i) {
            int off = (wr*64 + i*16 + lr)*40 + lk*8;
            ah[i] = *(const short8v*)&AsH[off];
            al[i] = *(const short8v*)&AsL[off];
        }
#pragma unroll
        for (int j = 0; j < 2; ++j) {
            int off = (wc*32 + j*16 + lr)*40 + lk*8;
            bh[j] = *(const short8v*)&BsH[off];
            bl[j] = *(const short8v*)&BsL[off];
        }
        __builtin_amdgcn_s_setprio(1);
#pragma unroll
        for (int i = 0; i < 4; ++i)
#pragma unroll
            for (int j = 0; j < 2; ++j) {
                acc[i][j] = __builtin_amdgcn_mfma_f32_16x16x32_bf16(ah[i], bh[j], acc[i][j], 0, 0, 0);
                acc[i][j] = __builtin_amdgcn_mfma_f32_16x16x32_bf16(ah[i], bl[j], acc[i][j], 0, 0, 0);
                acc[i][j] = __builtin_amdgcn_mfma_f32_16x16x32_bf16(al[i], bh[j], acc[i][j], 0, 0, 0);
            }
        __builtin_amdgcn_s_setprio(0);
    }

    float bj[2];
#pragma unroll
    for (int j = 0; j < 2; ++j) bj[j] = bias ? bias[n0 + wc*32 + j*16 + lr] : 0.0f;
#pragma unroll
    for (int i = 0; i < 4; ++i)
#pragma unroll
        for (int j = 0; j < 2; ++j) {
            int col = n0 + wc*32 + j*16 + lr;
#pragma unroll
            for (int r = 0; r < 4; ++r) {
                int row = m0 + wr*64 + i*16 + lk*4 + r;
                float v = acc[i][j][r] + bj[j];
                size_t o = (size_t)row * N + col;
                if constexpr (OUT_MODE == 0) {
                    C[o] = v;
                } else {
                    u16 h = f2bf(v);
                    Ch[o] = h;
                    Cl[o] = f2bf(v - bf2f(h));
                }
            }
        }
}

// ---------------------------------------------------------------------------
// GEMM with fp32 A input (split performed during LDS staging). B split [N][K].
// ---------------------------------------------------------------------------
template<int OUT_MODE>
__global__ __launch_bounds__(256) void gemm_f32a(
    const float* __restrict__ A,
    const u16* __restrict__ Bh, const u16* __restrict__ Bl,
    const float* __restrict__ bias, float* __restrict__ C,
    u16* __restrict__ Ch, u16* __restrict__ Cl)
{
    constexpr int K = 1024, N = 1024;
    __shared__ u16 AsH[128*40], AsL[128*40], BsH[64*40], BsL[64*40];

    const int t = threadIdx.x;
    const int m0 = blockIdx.y * 128;
    const int n0 = blockIdx.x * 64;
    const int lane = t & 63, w = t >> 6;
    const int wr = w >> 1, wc = w & 1;
    const int lr = lane & 15, lk = lane >> 4;

    f32x4 acc[4][2];
#pragma unroll
    for (int i = 0; i < 4; ++i)
#pragma unroll
        for (int j = 0; j < 2; ++j) acc[i][j] = (f32x4){0.f,0.f,0.f,0.f};

    for (int k0 = 0; k0 < K; k0 += 32) {
        __syncthreads();
#pragma unroll
        for (int r = 0; r < 2; ++r) {
            int j = r*256 + t;               // 0..511 groups of 8 floats
            int row = j >> 2, c8 = j & 3;
            const float* src = &A[(size_t)(m0 + row) * K + k0 + c8*8];
            float4 a = *(const float4*)src;
            float4 b = *(const float4*)(src + 4);
            float xs[8] = {a.x,a.y,a.z,a.w,b.x,b.y,b.z,b.w};
            short8v hv, lv;
#pragma unroll
            for (int jj = 0; jj < 8; ++jj) {
                u16 h = f2bf(xs[jj]);
                hv[jj] = (short)h;
                lv[jj] = (short)f2bf(xs[jj] - bf2f(h));
            }
            *(short8v*)&AsH[row*40 + c8*8] = hv;
            *(short8v*)&AsL[row*40 + c8*8] = lv;
        }
        {
            int row = t >> 2, c = t & 3;
            size_t g = (size_t)(n0 + row) * K + k0 + c*8;
            *(short8v*)&BsH[row*40 + c*8] = *(const short8v*)&Bh[g];
            *(short8v*)&BsL[row*40 + c*8] = *(const short8v*)&Bl[g];
        }
        __syncthreads();

        short8v ah[4], al[4], bh[2], bl[2];
#pragma unroll
        for (int i = 0; i < 4; ++i) {
            int off = (wr*64 + i*16 + lr)*40 + lk*8;
            ah[i] = *(const short8v*)&AsH[off];
            al[i] = *(const short8v*)&AsL[off];
        }
#pragma unroll
        for (int j = 0; j < 2; ++j) {
            int off = (wc*32 + j*16 + lr)*40 + lk*8;
            bh[j] = *(const short8v*)&BsH[off];
            bl[j] = *(const short8v*)&BsL[off];
        }
        __builtin_amdgcn_s_setprio(1);
#pragma unroll
        for (int i = 0; i < 4; ++i)
#pragma unroll
            for (int j = 0; j < 2; ++j) {
                acc[i][j] = __builtin_amdgcn_mfma_f32_16x16x32_bf16(ah[i], bh[j], acc[i][j], 0, 0, 0);
                acc[i][j] = __builtin_amdgcn_mfma_f32_16x16x32_bf16(ah[i], bl[j], acc[i][j], 0, 0, 0);
                acc[i][j] = __builtin_amdgcn_mfma_f32_16x16x32_bf16(al[i], bh[j], acc[i][j], 0, 0, 0);
            }
        __builtin_amdgcn_s_setprio(0);
    }

    float bj[2];
#pragma unroll
    for (int j = 0; j < 2; ++j) bj[j] = bias ? bias[n0 + wc*32 + j*16 + lr] : 0.0f;
#pragma unroll
    for (int i = 0; i < 4; ++i)
#pragma unroll
        for (int j = 0; j < 2; ++j) {
            int col = n0 + wc*32 + j*16 + lr;
#pragma unroll
            for (int r = 0; r < 4; ++r) {
                int row = m0 + wr*64 + i*16 + lk*4 + r;
                float v = acc[i][j][r] + bj[j];
                size_t o = (size_t)row * N + col;
                if constexpr (OUT_MODE == 0) {
                    C[o] = v;
                } else {
                    u16 h = f2bf(v);
                    Ch[o] = h;
                    Cl[o] = f2bf(v - bf2f(h));
                }
            }
        }
}

// ---------------------------------------------------------------------------
// Fused LayerNorm -> per-head softmax; bf16 outputs in BHSD layout.
// MODE 0: q_prob hi/lo + ENT ; MODE 1: log(prob+eps) hi/lo ; MODE 2: LN bf16.
// ---------------------------------------------------------------------------
template<int MODE>
__global__ __launch_bounds__(256) void ln_head_kernel(
    const float* __restrict__ X, const float* __restrict__ G,
    const float* __restrict__ Bt, u16* __restrict__ OA,
    u16* __restrict__ OB, float* __restrict__ ENT)
{
    const int row = blockIdx.x;
    const int tid = threadIdx.x;
    const float* x = X + (size_t)row * DM;
    float4 v = *(const float4*)&x[tid*4];

    float s  = v.x + v.y + v.z + v.w;
    float ss = v.x*v.x + v.y*v.y + v.z*v.z + v.w*v.w;
#pragma unroll
    for (int m = 1; m < 64; m <<= 1) { s += __shfl_xor(s, m); ss += __shfl_xor(ss, m); }
    __shared__ float redS[4], redQ[4];
    const int wave = tid >> 6, lane = tid & 63;
    if (lane == 0) { redS[wave] = s; redQ[wave] = ss; }
    __syncthreads();
    s  = redS[0] + redS[1] + redS[2] + redS[3];
    ss = redQ[0] + redQ[1] + redQ[2] + redQ[3];
    const float mu   = s * (1.0f / DM);
    const float var  = ss * (1.0f / DM) - mu * mu;
    const float rsig = rsqrtf(var + 1e-6f);

    float4 gv = *(const float4*)&G[tid*4];
    float4 bv = *(const float4*)&Bt[tid*4];
    float y0 = (v.x - mu) * rsig * gv.x + bv.x;
    float y1 = (v.y - mu) * rsig * gv.y + bv.y;
    float y2 = (v.z - mu) * rsig * gv.z + bv.z;
    float y3 = (v.w - mu) * rsig * gv.w + bv.w;

    const int b  = row >> 11;
    const int sl = row & (SEQ - 1);
    const int h  = tid >> 4;
    const size_t obase = (((size_t)(b*NH + h)) * SEQ + sl) * DEPTH + (tid & 15) * 4;

    if constexpr (MODE == 2) {
        unsigned w0 = (unsigned)f2bf(y0) | ((unsigned)f2bf(y1) << 16);
        unsigned w1 = (unsigned)f2bf(y2) | ((unsigned)f2bf(y3) << 16);
        *(uint2*)&OA[obase] = make_uint2(w0, w1);
    } else {
        float mx = fmaxf(fmaxf(y0, y1), fmaxf(y2, y3));
#pragma unroll
        for (int m = 1; m < 16; m <<= 1) mx = fmaxf(mx, __shfl_xor(mx, m, 16));
        float e0 = expf(y0 - mx), e1 = expf(y1 - mx), e2 = expf(y2 - mx), e3 = expf(y3 - mx);
        float se = e0 + e1 + e2 + e3;
#pragma unroll
        for (int m = 1; m < 16; m <<= 1) se += __shfl_xor(se, m, 16);
        float inv = 1.0f / se;
        float p0 = e0*inv, p1 = e1*inv, p2 = e2*inv, p3 = e3*inv;
        float o0, o1, o2, o3;
        if constexpr (MODE == 0) { o0 = p0; o1 = p1; o2 = p2; o3 = p3; }
        else {
            o0 = logf(p0 + 2e-8f); o1 = logf(p1 + 2e-8f);
            o2 = logf(p2 + 2e-8f); o3 = logf(p3 + 2e-8f);
        }
        u16 h0 = f2bf(o0), h1 = f2bf(o1), h2 = f2bf(o2), h3 = f2bf(o3);
        unsigned w0 = (unsigned)h0 | ((unsigned)h1 << 16);
        unsigned w1 = (unsigned)h2 | ((unsigned)h3 << 16);
        *(uint2*)&OA[obase] = make_uint2(w0, w1);
        u16 l0 = f2bf(o0 - bf2f(h0)), l1 = f2bf(o1 - bf2f(h1));
        u16 l2 = f2bf(o2 - bf2f(h2)), l3 = f2bf(o3 - bf2f(h3));
        w0 = (unsigned)l0 | ((unsigned)l1 << 16);
        w1 = (unsigned)l2 | ((unsigned)l3 << 16);
        *(uint2*)&OB[obase] = make_uint2(w0, w1);

        if constexpr (MODE == 0) {
            float lse = logf(se);
            float el = p0*(y0-mx-lse) + p1*(y1-mx-lse) + p2*(y2-mx-lse) + p3*(y3-mx-lse);
#pragma unroll
            for (int m = 1; m < 16; m <<= 1) el += __shfl_xor(el, m, 16);
            if ((tid & 15) == 0) ENT[((size_t)(b*NH + h)) * SEQ + sl] = el;
        }
    }
}

// ---------------------------------------------------------------------------
// V transpose via LDS: Vb [bh][s][d] bf16 -> VT [bh][d][s] bf16 (coalesced)
// ---------------------------------------------------------------------------
__global__ __launch_bounds__(256) void vtrans_kernel(
    const u16* __restrict__ Vb, u16* __restrict__ VT)
{
    __shared__ u16 T[256*72];
    const int bh = blockIdx.y;
    const int s0 = blockIdx.x * 256;
    const int t  = threadIdx.x;
#pragma unroll
    for (int i = 0; i < 8; ++i) {
        int c = i*256 + t;
        int s = c >> 3, d0 = (c & 7) * 8;
        *(short8v*)&T[s*72 + d0] =
            *(const short8v*)&Vb[((size_t)bh*SEQ + s0 + s)*DEPTH + d0];
    }
    __syncthreads();
#pragma unroll
    for (int i = 0; i < 8; ++i) {
        int c = i*256 + t;
        int d = c >> 5, sl0 = (c & 31) * 8;
        short8v v;
#pragma unroll
        for (int j = 0; j < 8; ++j) v[j] = (short)T[(sl0 + j)*72 + d];
        *(short8v*)&VT[((size_t)bh*DEPTH + d)*SEQ + s0 + sl0] = v;
    }
}

// ---------------------------------------------------------------------------
// attn6: two-phase MFMA attention + T14 async-STAGE (prefetch next chunk into
// regs before compute, ds_write after the read-barrier). 2 barriers/chunk.
// ---------------------------------------------------------------------------
__global__ __launch_bounds__(256, 4) void attn6_kernel(
    const u16* __restrict__ QPh, const u16* __restrict__ QPl,
    const u16* __restrict__ LKh, const u16* __restrict__ LKl,
    const u16* __restrict__ VT, const float* __restrict__ ENT,
    float* __restrict__ ATTN, u16* __restrict__ OH, u16* __restrict__ OL)
{
    // XCD-aware bijective swizzle (1024 wgs, 8 XCDs, 128 contiguous each)
    const int wg   = blockIdx.x;
    const int wgid = (wg & 7) * 128 + (wg >> 3);
    const int bh   = wgid >> 5;
    const int q0   = (wgid & 31) * 64;

    const int t  = threadIdx.x;
    const int l  = t & 63, w = t >> 6;
    const int lr = l & 15, lg = l >> 4;
    const size_t rbase = (size_t)bh * SEQ;

    __shared__ u16 KhS[64*64], KlS[64*64], VtS[64*64], PS[64*64];

    // staging slot map: two slots per thread
    const int kr0 = t >> 3,           c0 = t & 7;          // rows 0..31
    const int kr1 = (256 + t) >> 3,   c1 = t & 7;          // rows 32..63
    const int wz0 = SWZ(kr0, c0*16), wz1 = SWZ(kr1, c1*16);

    // Q fragments + entropy (loop-invariant, registers)
    short8v qh[2], ql[2];
#pragma unroll
    for (int d = 0; d < 2; ++d) {
        size_t g = (rbase + q0 + w*16 + lr) * DEPTH + d*32 + lg*8;
        qh[d] = *(const short8v*)&QPh[g];
        ql[d] = *(const short8v*)&QPl[g];
    }
    float e8[4];
#pragma unroll
    for (int r = 0; r < 4; ++r)
        e8[r] = ENT[rbase + q0 + w*16 + lg*4 + r] * 0.125f;

    // ---------------- phase A: rowsums ----------------
    {   // prologue: stage chunk 0
        size_t g0 = (rbase + kr0) * DEPTH + c0*8;
        size_t g1 = (rbase + kr1) * DEPTH + c1*8;
        *(short8v*)((char*)KhS + wz0) = *(const short8v*)&LKh[g0];
        *(short8v*)((char*)KlS + wz0) = *(const short8v*)&LKl[g0];
        *(short8v*)((char*)KhS + wz1) = *(const short8v*)&LKh[g1];
        *(short8v*)((char*)KlS + wz1) = *(const short8v*)&LKl[g1];
    }
    __syncthreads();

    float rs[4] = {0.f, 0.f, 0.f, 0.f};
    for (int k0 = 0; k0 < SEQ; k0 += 64) {
        const bool more = (k0 + 64) < SEQ;
        short8v ph0, pl0, ph1, pl1;
        if (more) {     // T14: issue next-chunk loads before compute
            size_t g0 = (rbase + k0 + 64 + kr0) * DEPTH + c0*8;
            size_t g1 = (rbase + k0 + 64 + kr1) * DEPTH + c1*8;
            ph0 = *(const short8v*)&LKh[g0]; pl0 = *(const short8v*)&LKl[g0];
            ph1 = *(const short8v*)&LKh[g1]; pl1 = *(const short8v*)&LKl[g1];
        }

        f32x4 acc[4];
#pragma unroll
        for (int f = 0; f < 4; ++f) acc[f] = (f32x4){0.f,0.f,0.f,0.f};
        __builtin_amdgcn_s_setprio(1);
#pragma unroll
        for (int f = 0; f < 4; ++f)
#pragma unroll
            for (int d = 0; d < 2; ++d) {
                int off = SWZ(f*16 + lr, d*64 + lg*16);
                short8v kbh = *(const short8v*)((const char*)KhS + off);
                short8v kbl = *(const short8v*)((const char*)KlS + off);
                acc[f] = __builtin_amdgcn_mfma_f32_16x16x32_bf16(qh[d], kbh, acc[f], 0, 0, 0);
                acc[f] = __builtin_amdgcn_mfma_f32_16x16x32_bf16(qh[d], kbl, acc[f], 0, 0, 0);
                acc[f] = __builtin_amdgcn_mfma_f32_16x16x32_bf16(ql[d], kbh, acc[f], 0, 0, 0);
            }
        __builtin_amdgcn_s_setprio(0);
#pragma unroll
        for (int f = 0; f < 4; ++f)
#pragma unroll
            for (int r = 0; r < 4; ++r)
                rs[r] += fast_csch(fmaf(acc[f][r], -0.125f, e8[r]));

        __syncthreads();          // all reads of current chunk done
        if (more) {
            *(short8v*)((char*)KhS + wz0) = ph0;
            *(short8v*)((char*)KlS + wz0) = pl0;
            *(short8v*)((char*)KhS + wz1) = ph1;
            *(short8v*)((char*)KlS + wz1) = pl1;
            __syncthreads();      // writes visible
        }
    }
#pragma unroll
    for (int m = 1; m < 16; m <<= 1)
#pragma unroll
        for (int r = 0; r < 4; ++r) rs[r] += __shfl_xor(rs[r], m, 16);
    float inv[4];
#pragma unroll
    for (int r = 0; r < 4; ++r) inv[r] = 1.0f / rs[r];

    // ---------------- phase B: normalized write + PV ----------------
    {   // prologue: stage K chunk 0 + V chunk 0 (phase A's final barrier passed)
        size_t g0 = (rbase + kr0) * DEPTH + c0*8;
        size_t g1 = (rbase + kr1) * DEPTH + c1*8;
        *(short8v*)((char*)KhS + wz0) = *(const short8v*)&LKh[g0];
        *(short8v*)((char*)KlS + wz0) = *(const short8v*)&LKl[g0];
        *(short8v*)((char*)KhS + wz1) = *(const short8v*)&LKh[g1];
        *(short8v*)((char*)KlS + wz1) = *(const short8v*)&LKl[g1];
        size_t v0 = ((size_t)bh * DEPTH + kr0) * SEQ + c0*8;
        size_t v1 = ((size_t)bh * DEPTH + kr1) * SEQ + c1*8;
        *(short8v*)((char*)VtS + wz0) = *(const short8v*)&VT[v0];
        *(short8v*)((char*)VtS + wz1) = *(const short8v*)&VT[v1];
    }
    __syncthreads();

    f32x4 av[4];
#pragma unroll
    for (int nf = 0; nf < 4; ++nf) av[nf] = (f32x4){0.f,0.f,0.f,0.f};

    for (int k0 = 0; k0 < SEQ; k0 += 64) {
        const bool more = (k0 + 64) < SEQ;
        short8v ph0, pl0, ph1, pl1, pv0, pv1;
        if (more) {
            size_t g0 = (rbase + k0 + 64 + kr0) * DEPTH + c0*8;
            size_t g1 = (rbase + k0 + 64 + kr1) * DEPTH + c1*8;
            ph0 = *(const short8v*)&LKh[g0]; pl0 = *(const short8v*)&LKl[g0];
            ph1 = *(const short8v*)&LKh[g1]; pl1 = *(const short8v*)&LKl[g1];
            size_t v0 = ((size_t)bh * DEPTH + kr0) * SEQ + k0 + 64 + c0*8;
            size_t v1 = ((size_t)bh * DEPTH + kr1) * SEQ + k0 + 64 + c1*8;
            pv0 = *(const short8v*)&VT[v0];
            pv1 = *(const short8v*)&VT[v1];
        }

        f32x4 acc[4];
#pragma unroll
        for (int f = 0; f < 4; ++f) acc[f] = (f32x4){0.f,0.f,0.f,0.f};
        __builtin_amdgcn_s_setprio(1);
#pragma unroll
        for (int f = 0; f < 4; ++f)
#pragma unroll
            for (int d = 0; d < 2; ++d) {
                int off = SWZ(f*16 + lr, d*64 + lg*16);
                short8v kbh = *(const short8v*)((const char*)KhS + off);
                short8v kbl = *(const short8v*)((const char*)KlS + off);
                acc[f] = __builtin_amdgcn_mfma_f32_16x16x32_bf16(qh[d], kbh, acc[f], 0, 0, 0);
                acc[f] = __builtin_amdgcn_mfma_f32_16x16x32_bf16(qh[d], kbl, acc[f], 0, 0, 0);
                acc[f] = __builtin_amdgcn_mfma_f32_16x16x32_bf16(ql[d], kbh, acc[f], 0, 0, 0);
            }
        __builtin_amdgcn_s_setprio(0);

        // csch + normalized ATTN write + PS (own-wave rows; no barrier needed)
#pragma unroll
        for (int f = 0; f < 4; ++f)
#pragma unroll
            for (int r = 0; r < 4; ++r) {
                float c = fast_csch(fmaf(acc[f][r], -0.125f, e8[r]));
                float a = c * inv[r];
                int q = w*16 + lg*4 + r;
                ATTN[(rbase + q0 + q) * SEQ + k0 + f*16 + lr] = a;
                *(u16*)((char*)PS + SWZ(q, (f*16 + lr)*2)) = f2bf(a);
            }

        short8v pa[2];
#pragma unroll
        for (int ks = 0; ks < 2; ++ks)
            pa[ks] = *(const short8v*)((const char*)PS + SWZ(w*16 + lr, ks*64 + lg*16));
        __builtin_amdgcn_s_setprio(1);
#pragma unroll
        for (int nf = 0; nf < 4; ++nf)
#pragma unroll
            for (int ks = 0; ks < 2; ++ks) {
                short8v vb = *(const short8v*)((const char*)VtS + SWZ(nf*16 + lr, ks*64 + lg*16));
                av[nf] = __builtin_amdgcn_mfma_f32_16x16x32_bf16(pa[ks], vb, av[nf], 0, 0, 0);
            }
        __builtin_amdgcn_s_setprio(0);

        __syncthreads();
        if (more) {
            *(short8v*)((char*)KhS + wz0) = ph0;
            *(short8v*)((char*)KlS + wz0) = pl0;
            *(short8v*)((char*)KhS + wz1) = ph1;
            *(short8v*)((char*)KlS + wz1) = pl1;
            *(short8v*)((char*)VtS + wz0) = pv0;
            *(short8v*)((char*)VtS + wz1) = pv1;
            __syncthreads();
        }
    }

    // OV write: normalized, (B,S,DM) layout, split bf16
    const int b = bh >> 4, h = bh & (NH - 1);
#pragma unroll
    for (int nf = 0; nf < 4; ++nf)
#pragma unroll
        for (int r = 0; r < 4; ++r) {
            int q = w*16 + lg*4 + r;
            int d = nf*16 + lr;
            size_t o = ((size_t)(b * SEQ + q0 + q)) * DM + h * DEPTH + d;
            float v = av[nf][r];
            u16 hh = f2bf(v);
            OH[o] = hh;
            OL[o] = f2bf(v - bf2f(hh));
        }
}

// ---------------------------------------------------------------------------
extern "C" void kernel_launch(void* const* d_in, const int* in_sizes, int n_in,
                              void* d_out, int out_size, void* d_ws, size_t ws_size,
                              hipStream_t stream)
{
    const float* q_in = (const float*)d_in[0];
    const float* k_in = (const float*)d_in[1];
    const float* Wq = (const float*)d_in[2];
    const float* bq = (const float*)d_in[3];
    const float* Wk = (const float*)d_in[4];
    const float* bk = (const float*)d_in[5];
    const float* Wv = (const float*)d_in[6];
    const float* bvp = (const float*)d_in[7];
    const float* Wo = (const float*)d_in[8];
    const float* bo = (const float*)d_in[9];
    const float* g1 = (const float*)d_in[10];
    const float* b1 = (const float*)d_in[11];
    const float* g2 = (const float*)d_in[12];
    const float* b2 = (const float*)d_in[13];
    const float* g3 = (const float*)d_in[14];
    const float* b3 = (const float*)d_in[15];

    float* out0 = (float*)d_out;                     // (B,S,DM)
    float* attn = out0 + (size_t)ROWS * DM;          // (B,H,S,S)

    char* base = (char*)d_ws;
    const size_t SLOT = (size_t)ROWS * DM * 4;       // 16 MB
    const size_t HALF = (size_t)ROWS * DM;           // 4M u16 elements
    float* S0f = (float*)(base);
    float* S1f = (float*)(base + SLOT);
    float* S2f = (float*)(base + 2*SLOT);
    float* S3f = (float*)(base + 3*SLOT);
    u16* S0h = (u16*)S0f; u16* S0l = S0h + HALF;
    u16* S1h = (u16*)S1f;
    u16* S3h = (u16*)S3f; u16* S3l = S3h + HALF;
    // attention operand views
    u16* QPh = (u16*)S3f; u16* QPl = QPh + HALF;
    u16* LKh = (u16*)S2f; u16* LKl = LKh + HALF;
    u16* Vb  = (u16*)S0f; u16* VTp = Vb + HALF;
    u16* OHp = (u16*)S1f; u16* OLp = OHp + HALF;
    // non-transposed Wq split (temporary, lives in S0 before k2 is produced)
    u16* WqnH = S0h;                                 // 1M u16 each (2 MB)
    u16* WqnL = S0h + (size_t)DM*DM;

    char* wbase = base + 4*SLOT;
    const size_t WSZ = (size_t)DM * DM * 2;          // 2 MB per bf16 matrix
    u16* WqH = (u16*)(wbase);           u16* WqL = (u16*)(wbase + WSZ);
    u16* WkH = (u16*)(wbase + 2*WSZ);   u16* WkL = (u16*)(wbase + 3*WSZ);
    u16* WvH = (u16*)(wbase + 4*WSZ);   u16* WvL = (u16*)(wbase + 5*WSZ);
    u16* WoH = (u16*)(wbase + 6*WSZ);   u16* WoL = (u16*)(wbase + 7*WSZ);
    u16* W2H = (u16*)(wbase + 8*WSZ);   u16* W2L = (u16*)(wbase + 9*WSZ);
    float* ent = (float*)(wbase + 10*WSZ);
    float* bq2 = ent + BHS;

    const dim3 ggrid(DM/64, ROWS/128);               // (16, 32)
    const dim3 g2grid(DM/64, DM/128);                // (16, 8)

    // weights: transpose+split (x4 in one launch) + non-transposed Wq split
    wsplit4_kernel<<<dim3(32,32,4), 256, 0, stream>>>(
        Wq, Wk, Wv, Wo, WqH, WqL, WkH, WkL, WvH, WvL, WoH, WoL);
    split_kernel<<<DM*DM/(4*256), 256, 0, stream>>>(Wq, WqnH, WqnL);
    bias2_kernel<<<16, 256, 0, stream>>>(bq, Wq, bq2);
    // W2^T = Wq^T @ Wq^T  (A = WqT split, B = Wq non-transposed split)
    gemm_mfma<1><<<g2grid, 256, 0, stream>>>(WqH, WqL, WqnH, WqnL, nullptr,
                                             nullptr, W2H, W2L);

    // q2 = q_in @ W2 + bq2 (fp32 -> S2f)
    gemm_f32a<0><<<ggrid, 256, 0, stream>>>(q_in, W2H, W2L, bq2, S2f, nullptr, nullptr);
    // k1 = k_in @ Wk + bk (split -> S3)
    gemm_f32a<1><<<ggrid, 256, 0, stream>>>(k_in, WkH, WkL, bk, nullptr, S3h, S3l);
    // k2 = k1 @ Wk + bk (fp32 -> S0f) ; v = k1 @ Wv + bv (fp32 -> S1f)
    gemm_mfma<0><<<ggrid, 256, 0, stream>>>(S3h, S3l, WkH, WkL, bk, S0f, nullptr, nullptr);
    gemm_mfma<0><<<ggrid, 256, 0, stream>>>(S3h, S3l, WvH, WvL, bvp, S1f, nullptr, nullptr);

    // LN + head softmax -> bf16 BHSD operands
    ln_head_kernel<0><<<ROWS, 256, 0, stream>>>(S2f, g1, b1, QPh, QPl, ent);
    ln_head_kernel<1><<<ROWS, 256, 0, stream>>>(S0f, g2, b2, LKh, LKl, nullptr);
    ln_head_kernel<2><<<ROWS, 256, 0, stream>>>(S1f, g3, b3, Vb, nullptr, nullptr);
    vtrans_kernel<<<dim3(SEQ/256, BS*NH), 256, 0, stream>>>(Vb, VTp);

    // fused attention (normalized attn + normalized split OV)
    attn6_kernel<<<dim3(SEQ/64 * BS*NH), 256, 0, stream>>>(
        QPh, QPl, LKh, LKl, VTp, ent, attn, OHp, OLp);

    // final projection
    gemm_mfma<0><<<ggrid, 256, 0, stream>>>(OHp, OLp, WoH, WoL, bo, out0, nullptr, nullptr);
}

// Round 8
// 573.633 us; speedup vs baseline: 1.0549x; 1.0549x over previous
//
#include <hip/hip_runtime.h>
#include <cstddef>
#include <cstdint>

#define BS      2
#define SEQ     2048
#define DM      1024
#define NH      16
#define DEPTH   64
#define ROWS    (BS*SEQ)          // 4096
#define BHS     (BS*NH*SEQ)       // 65536

typedef unsigned short u16;
typedef __attribute__((ext_vector_type(8))) short short8v;
typedef __attribute__((ext_vector_type(4))) float f32x4;

// swizzled byte offset into a [64 rows][128 B] LDS tile (T2 / G4 fix)
#define SWZ(row, cb) ((((row) << 7)) | ((cb) ^ (((row) & 7) << 4)))

__device__ __forceinline__ u16 f2bf(float x) {
    unsigned u = __builtin_bit_cast(unsigned, x);
    unsigned r = u + 0x7FFFu + ((u >> 16) & 1u);
    return (u16)(r >> 16);
}
__device__ __forceinline__ float bf2f(u16 h) {
    unsigned u = ((unsigned)h) << 16;
    return __builtin_bit_cast(float, u);
}

// fast csch(x)=1/sinh(x): big path 2t/(t^2-1), t=e^x; small |x|<0.04: 1/x - x/6.
__device__ __forceinline__ float fast_csch(float x) {
    float t    = __expf(x);
    float den  = fmaf(t, t, -1.0f);
    bool  sm   = fabsf(x) < 0.04f;
    float d    = sm ? x : den;
    float r    = __builtin_amdgcn_rcpf(d);
    float big  = 2.0f * t * r;
    float smal = fmaf(x, -(1.0f/6.0f), r);
    return sm ? smal : big;
}

// ---------------------------------------------------------------------------
// All weight prep in ONE launch (z = 0..5):
//  z<4 : transpose+split W[z] -> [N][K] bf16 hi/lo
//  z=4 : elementwise split of Wq (non-transposed) -- grid 32x32 == 1024 blocks
//  z=5 : bias2[n] = bq[n] + sum_k bq[k]*Wq[k][n]  (blocks (bx<16, by==0))
// ---------------------------------------------------------------------------
__global__ __launch_bounds__(256) void wprep_kernel(
    const float* __restrict__ W0, const float* __restrict__ W1,
    const float* __restrict__ W2_, const float* __restrict__ W3,
    const float* __restrict__ bq,
    u16* __restrict__ H0, u16* __restrict__ L0, u16* __restrict__ H1, u16* __restrict__ L1,
    u16* __restrict__ H2, u16* __restrict__ L2, u16* __restrict__ H3, u16* __restrict__ L3,
    u16* __restrict__ HN, u16* __restrict__ LN_, float* __restrict__ bq2)
{
    const int z = blockIdx.z;
    if (z == 4) {
        int bid = blockIdx.y * 32 + blockIdx.x;
        int i = bid * 256 + threadIdx.x;           // float4 index over DM*DM/4
        float4 v = ((const float4*)W0)[i];
        u16 h0 = f2bf(v.x), h1 = f2bf(v.y), h2 = f2bf(v.z), h3 = f2bf(v.w);
        u16 l0 = f2bf(v.x - bf2f(h0)), l1 = f2bf(v.y - bf2f(h1));
        u16 l2 = f2bf(v.z - bf2f(h2)), l3 = f2bf(v.w - bf2f(h3));
        uint2 hh, ll;
        hh.x = (unsigned)h0 | ((unsigned)h1 << 16); hh.y = (unsigned)h2 | ((unsigned)h3 << 16);
        ll.x = (unsigned)l0 | ((unsigned)l1 << 16); ll.y = (unsigned)l2 | ((unsigned)l3 << 16);
        ((uint2*)HN)[i] = hh;
        ((uint2*)LN_)[i] = ll;
        return;
    }
    if (z == 5) {
        if (blockIdx.y != 0 || blockIdx.x >= 16) return;
        __shared__ float part[4][64];
        const int t = threadIdx.x;
        const int nl = t & 63, kk = t >> 6;
        const int n = blockIdx.x * 64 + nl;
        float acc = 0.0f;
#pragma unroll 8
        for (int k = kk*256; k < kk*256 + 256; ++k)
            acc = fmaf(bq[k], W0[(size_t)k * DM + n], acc);
        part[kk][nl] = acc;
        __syncthreads();
        if (t < 64)
            bq2[blockIdx.x*64 + t] = part[0][t] + part[1][t] + part[2][t] + part[3][t]
                                   + bq[blockIdx.x*64 + t];
        return;
    }
    const float* W; u16* H; u16* L;
    switch (z) {
        case 0: W = W0; H = H0; L = L0; break;
        case 1: W = W1; H = H1; L = L1; break;
        case 2: W = W2_; H = H2; L = L2; break;
        default: W = W3; H = H3; L = L3; break;
    }
    __shared__ float tile[32][33];
    const int bn = blockIdx.x, bk = blockIdx.y;
    const int c = threadIdx.x & 31, r0 = threadIdx.x >> 5;
#pragma unroll
    for (int r = 0; r < 32; r += 8)
        tile[r0 + r][c] = W[(size_t)(bk*32 + r0 + r) * DM + bn*32 + c];
    __syncthreads();
#pragma unroll
    for (int r = 0; r < 32; r += 8) {
        float v = tile[c][r0 + r];
        u16 h = f2bf(v);
        size_t o = (size_t)(bn*32 + r0 + r) * DM + bk*32 + c;
        H[o] = h;
        L[o] = f2bf(v - bf2f(h));
    }
}

// ---------------------------------------------------------------------------
// Split-bf16 MFMA GEMM: C = A@W (+ bias). A split bf16 [M][K]; B split [N][K].
// ---------------------------------------------------------------------------
template<int OUT_MODE>
__global__ __launch_bounds__(256) void gemm_mfma(
    const u16* __restrict__ Ah, const u16* __restrict__ Al,
    const u16* __restrict__ Bh, const u16* __restrict__ Bl,
    const float* __restrict__ bias, float* __restrict__ C,
    u16* __restrict__ Ch, u16* __restrict__ Cl)
{
    constexpr int K = 1024, N = 1024;
    __shared__ u16 AsH[128*40], AsL[128*40], BsH[64*40], BsL[64*40];

    const int t = threadIdx.x;
    const int m0 = blockIdx.y * 128;
    const int n0 = blockIdx.x * 64;
    const int lane = t & 63, w = t >> 6;
    const int wr = w >> 1, wc = w & 1;
    const int lr = lane & 15, lk = lane >> 4;

    f32x4 acc[4][2];
#pragma unroll
    for (int i = 0; i < 4; ++i)
#pragma unroll
        for (int j = 0; j < 2; ++j) acc[i][j] = (f32x4){0.f,0.f,0.f,0.f};

    for (int k0 = 0; k0 < K; k0 += 32) {
        __syncthreads();
#pragma unroll
        for (int r = 0; r < 2; ++r) {
            int s = r*256 + t;
            int row = s >> 2, c = s & 3;
            size_t g = (size_t)(m0 + row) * K + k0 + c*8;
            *(short8v*)&AsH[row*40 + c*8] = *(const short8v*)&Ah[g];
            *(short8v*)&AsL[row*40 + c*8] = *(const short8v*)&Al[g];
        }
        {
            int row = t >> 2, c = t & 3;
            size_t g = (size_t)(n0 + row) * K + k0 + c*8;
            *(short8v*)&BsH[row*40 + c*8] = *(const short8v*)&Bh[g];
            *(short8v*)&BsL[row*40 + c*8] = *(const short8v*)&Bl[g];
        }
        __syncthreads();

        short8v ah[4], al[4], bh[2], bl[2];
#pragma unroll
        for (int i = 0; i < 4; ++i) {
            int off = (wr*64 + i*16 + lr)*40 + lk*8;
            ah[i] = *(const short8v*)&AsH[off];
            al[i] = *(const short8v*)&AsL[off];
        }
#pragma unroll
        for (int j = 0; j < 2; ++j) {
            int off = (wc*32 + j*16 + lr)*40 + lk*8;
            bh[j] = *(const short8v*)&BsH[off];
            bl[j] = *(const short8v*)&BsL[off];
        }
        __builtin_amdgcn_s_setprio(1);
#pragma unroll
        for (int i = 0; i < 4; ++i)
#pragma unroll
            for (int j = 0; j < 2; ++j) {
                acc[i][j] = __builtin_amdgcn_mfma_f32_16x16x32_bf16(ah[i], bh[j], acc[i][j], 0, 0, 0);
                acc[i][j] = __builtin_amdgcn_mfma_f32_16x16x32_bf16(ah[i], bl[j], acc[i][j], 0, 0, 0);
                acc[i][j] = __builtin_amdgcn_mfma_f32_16x16x32_bf16(al[i], bh[j], acc[i][j], 0, 0, 0);
            }
        __builtin_amdgcn_s_setprio(0);
    }

    float bj[2];
#pragma unroll
    for (int j = 0; j < 2; ++j) bj[j] = bias ? bias[n0 + wc*32 + j*16 + lr] : 0.0f;
#pragma unroll
    for (int i = 0; i < 4; ++i)
#pragma unroll
        for (int j = 0; j < 2; ++j) {
            int col = n0 + wc*32 + j*16 + lr;
#pragma unroll
            for (int r = 0; r < 4; ++r) {
                int row = m0 + wr*64 + i*16 + lk*4 + r;
                float v = acc[i][j][r] + bj[j];
                size_t o = (size_t)row * N + col;
                if constexpr (OUT_MODE == 0) {
                    C[o] = v;
                } else {
                    u16 h = f2bf(v);
                    Ch[o] = h;
                    Cl[o] = f2bf(v - bf2f(h));
                }
            }
        }
}

// ---------------------------------------------------------------------------
// GEMM with fp32 A input (split performed during LDS staging). B split [N][K].
// ---------------------------------------------------------------------------
template<int OUT_MODE>
__global__ __launch_bounds__(256) void gemm_f32a(
    const float* __restrict__ A,
    const u16* __restrict__ Bh, const u16* __restrict__ Bl,
    const float* __restrict__ bias, float* __restrict__ C,
    u16* __restrict__ Ch, u16* __restrict__ Cl)
{
    constexpr int K = 1024, N = 1024;
    __shared__ u16 AsH[128*40], AsL[128*40], BsH[64*40], BsL[64*40];

    const int t = threadIdx.x;
    const int m0 = blockIdx.y * 128;
    const int n0 = blockIdx.x * 64;
    const int lane = t & 63, w = t >> 6;
    const int wr = w >> 1, wc = w & 1;
    const int lr = lane & 15, lk = lane >> 4;

    f32x4 acc[4][2];
#pragma unroll
    for (int i = 0; i < 4; ++i)
#pragma unroll
        for (int j = 0; j < 2; ++j) acc[i][j] = (f32x4){0.f,0.f,0.f,0.f};

    for (int k0 = 0; k0 < K; k0 += 32) {
        __syncthreads();
#pragma unroll
        for (int r = 0; r < 2; ++r) {
            int j = r*256 + t;               // 0..511 groups of 8 floats
            int row = j >> 2, c8 = j & 3;
            const float* src = &A[(size_t)(m0 + row) * K + k0 + c8*8];
            float4 a = *(const float4*)src;
            float4 b = *(const float4*)(src + 4);
            float xs[8] = {a.x,a.y,a.z,a.w,b.x,b.y,b.z,b.w};
            short8v hv, lv;
#pragma unroll
            for (int jj = 0; jj < 8; ++jj) {
                u16 h = f2bf(xs[jj]);
                hv[jj] = (short)h;
                lv[jj] = (short)f2bf(xs[jj] - bf2f(h));
            }
            *(short8v*)&AsH[row*40 + c8*8] = hv;
            *(short8v*)&AsL[row*40 + c8*8] = lv;
        }
        {
            int row = t >> 2, c = t & 3;
            size_t g = (size_t)(n0 + row) * K + k0 + c*8;
            *(short8v*)&BsH[row*40 + c*8] = *(const short8v*)&Bh[g];
            *(short8v*)&BsL[row*40 + c*8] = *(const short8v*)&Bl[g];
        }
        __syncthreads();

        short8v ah[4], al[4], bh[2], bl[2];
#pragma unroll
        for (int i = 0; i < 4; ++i) {
            int off = (wr*64 + i*16 + lr)*40 + lk*8;
            ah[i] = *(const short8v*)&AsH[off];
            al[i] = *(const short8v*)&AsL[off];
        }
#pragma unroll
        for (int j = 0; j < 2; ++j) {
            int off = (wc*32 + j*16 + lr)*40 + lk*8;
            bh[j] = *(const short8v*)&BsH[off];
            bl[j] = *(const short8v*)&BsL[off];
        }
        __builtin_amdgcn_s_setprio(1);
#pragma unroll
        for (int i = 0; i < 4; ++i)
#pragma unroll
            for (int j = 0; j < 2; ++j) {
                acc[i][j] = __builtin_amdgcn_mfma_f32_16x16x32_bf16(ah[i], bh[j], acc[i][j], 0, 0, 0);
                acc[i][j] = __builtin_amdgcn_mfma_f32_16x16x32_bf16(ah[i], bl[j], acc[i][j], 0, 0, 0);
                acc[i][j] = __builtin_amdgcn_mfma_f32_16x16x32_bf16(al[i], bh[j], acc[i][j], 0, 0, 0);
            }
        __builtin_amdgcn_s_setprio(0);
    }

    float bj[2];
#pragma unroll
    for (int j = 0; j < 2; ++j) bj[j] = bias ? bias[n0 + wc*32 + j*16 + lr] : 0.0f;
#pragma unroll
    for (int i = 0; i < 4; ++i)
#pragma unroll
        for (int j = 0; j < 2; ++j) {
            int col = n0 + wc*32 + j*16 + lr;
#pragma unroll
            for (int r = 0; r < 4; ++r) {
                int row = m0 + wr*64 + i*16 + lk*4 + r;
                float v = acc[i][j][r] + bj[j];
                size_t o = (size_t)row * N + col;
                if constexpr (OUT_MODE == 0) {
                    C[o] = v;
                } else {
                    u16 h = f2bf(v);
                    Ch[o] = h;
                    Cl[o] = f2bf(v - bf2f(h));
                }
            }
        }
}

// ---------------------------------------------------------------------------
// Fused LayerNorm -> per-head softmax; bf16 outputs in BHSD layout.
// MODE 0: q_prob hi/lo + ENT ; MODE 1: log(prob+eps) hi/lo ; MODE 2: LN bf16.
// ---------------------------------------------------------------------------
template<int MODE>
__global__ __launch_bounds__(256) void ln_head_kernel(
    const float* __restrict__ X, const float* __restrict__ G,
    const float* __restrict__ Bt, u16* __restrict__ OA,
    u16* __restrict__ OB, float* __restrict__ ENT)
{
    const int row = blockIdx.x;
    const int tid = threadIdx.x;
    const float* x = X + (size_t)row * DM;
    float4 v = *(const float4*)&x[tid*4];

    float s  = v.x + v.y + v.z + v.w;
    float ss = v.x*v.x + v.y*v.y + v.z*v.z + v.w*v.w;
#pragma unroll
    for (int m = 1; m < 64; m <<= 1) { s += __shfl_xor(s, m); ss += __shfl_xor(ss, m); }
    __shared__ float redS[4], redQ[4];
    const int wave = tid >> 6, lane = tid & 63;
    if (lane == 0) { redS[wave] = s; redQ[wave] = ss; }
    __syncthreads();
    s  = redS[0] + redS[1] + redS[2] + redS[3];
    ss = redQ[0] + redQ[1] + redQ[2] + redQ[3];
    const float mu   = s * (1.0f / DM);
    const float var  = ss * (1.0f / DM) - mu * mu;
    const float rsig = rsqrtf(var + 1e-6f);

    float4 gv = *(const float4*)&G[tid*4];
    float4 bv = *(const float4*)&Bt[tid*4];
    float y0 = (v.x - mu) * rsig * gv.x + bv.x;
    float y1 = (v.y - mu) * rsig * gv.y + bv.y;
    float y2 = (v.z - mu) * rsig * gv.z + bv.z;
    float y3 = (v.w - mu) * rsig * gv.w + bv.w;

    const int b  = row >> 11;
    const int sl = row & (SEQ - 1);
    const int h  = tid >> 4;
    const size_t obase = (((size_t)(b*NH + h)) * SEQ + sl) * DEPTH + (tid & 15) * 4;

    if constexpr (MODE == 2) {
        unsigned w0 = (unsigned)f2bf(y0) | ((unsigned)f2bf(y1) << 16);
        unsigned w1 = (unsigned)f2bf(y2) | ((unsigned)f2bf(y3) << 16);
        *(uint2*)&OA[obase] = make_uint2(w0, w1);
    } else {
        float mx = fmaxf(fmaxf(y0, y1), fmaxf(y2, y3));
#pragma unroll
        for (int m = 1; m < 16; m <<= 1) mx = fmaxf(mx, __shfl_xor(mx, m, 16));
        float e0 = expf(y0 - mx), e1 = expf(y1 - mx), e2 = expf(y2 - mx), e3 = expf(y3 - mx);
        float se = e0 + e1 + e2 + e3;
#pragma unroll
        for (int m = 1; m < 16; m <<= 1) se += __shfl_xor(se, m, 16);
        float inv = 1.0f / se;
        float p0 = e0*inv, p1 = e1*inv, p2 = e2*inv, p3 = e3*inv;
        float o0, o1, o2, o3;
        if constexpr (MODE == 0) { o0 = p0; o1 = p1; o2 = p2; o3 = p3; }
        else {
            o0 = logf(p0 + 2e-8f); o1 = logf(p1 + 2e-8f);
            o2 = logf(p2 + 2e-8f); o3 = logf(p3 + 2e-8f);
        }
        u16 h0 = f2bf(o0), h1 = f2bf(o1), h2 = f2bf(o2), h3 = f2bf(o3);
        unsigned w0 = (unsigned)h0 | ((unsigned)h1 << 16);
        unsigned w1 = (unsigned)h2 | ((unsigned)h3 << 16);
        *(uint2*)&OA[obase] = make_uint2(w0, w1);
        u16 l0 = f2bf(o0 - bf2f(h0)), l1 = f2bf(o1 - bf2f(h1));
        u16 l2 = f2bf(o2 - bf2f(h2)), l3 = f2bf(o3 - bf2f(h3));
        w0 = (unsigned)l0 | ((unsigned)l1 << 16);
        w1 = (unsigned)l2 | ((unsigned)l3 << 16);
        *(uint2*)&OB[obase] = make_uint2(w0, w1);

        if constexpr (MODE == 0) {
            float lse = logf(se);
            float el = p0*(y0-mx-lse) + p1*(y1-mx-lse) + p2*(y2-mx-lse) + p3*(y3-mx-lse);
#pragma unroll
            for (int m = 1; m < 16; m <<= 1) el += __shfl_xor(el, m, 16);
            if ((tid & 15) == 0) ENT[((size_t)(b*NH + h)) * SEQ + sl] = el;
        }
    }
}

// ---------------------------------------------------------------------------
// V transpose via LDS: Vb [bh][s][d] bf16 -> VT [bh][d][s] bf16 (coalesced)
// ---------------------------------------------------------------------------
__global__ __launch_bounds__(256) void vtrans_kernel(
    const u16* __restrict__ Vb, u16* __restrict__ VT)
{
    __shared__ u16 T[256*72];
    const int bh = blockIdx.y;
    const int s0 = blockIdx.x * 256;
    const int t  = threadIdx.x;
#pragma unroll
    for (int i = 0; i < 8; ++i) {
        int c = i*256 + t;
        int s = c >> 3, d0 = (c & 7) * 8;
        *(short8v*)&T[s*72 + d0] =
            *(const short8v*)&Vb[((size_t)bh*SEQ + s0 + s)*DEPTH + d0];
    }
    __syncthreads();
#pragma unroll
    for (int i = 0; i < 8; ++i) {
        int c = i*256 + t;
        int d = c >> 5, sl0 = (c & 31) * 8;
        short8v v;
#pragma unroll
        for (int j = 0; j < 8; ++j) v[j] = (short)T[(sl0 + j)*72 + d];
        *(short8v*)&VT[((size_t)bh*DEPTH + d)*SEQ + s0 + sl0] = v;
    }
}

// ---------------------------------------------------------------------------
// attn5: two-phase MFMA attention, swizzled LDS, cheap csch, Q in regs,
// XCD-chunked 1D grid, simple barrier-staged K/V.
// ---------------------------------------------------------------------------
__global__ __launch_bounds__(256, 4) void attn5_kernel(
    const u16* __restrict__ QPh, const u16* __restrict__ QPl,
    const u16* __restrict__ LKh, const u16* __restrict__ LKl,
    const u16* __restrict__ VT, const float* __restrict__ ENT,
    float* __restrict__ ATTN, u16* __restrict__ OH, u16* __restrict__ OL)
{
    const int wg   = blockIdx.x;
    const int wgid = (wg & 7) * 128 + (wg >> 3);
    const int bh   = wgid >> 5;
    const int q0   = (wgid & 31) * 64;

    const int t  = threadIdx.x;
    const int l  = t & 63, w = t >> 6;
    const int lr = l & 15, lg = l >> 4;
    const size_t rbase = (size_t)bh * SEQ;

    __shared__ u16 KhS[64*64], KlS[64*64], VtS[64*64], PS[64*64];

    short8v qh[2], ql[2];
#pragma unroll
    for (int d = 0; d < 2; ++d) {
        size_t g = (rbase + q0 + w*16 + lr) * DEPTH + d*32 + lg*8;
        qh[d] = *(const short8v*)&QPh[g];
        ql[d] = *(const short8v*)&QPl[g];
    }
    float e8[4];
#pragma unroll
    for (int r = 0; r < 4; ++r)
        e8[r] = ENT[rbase + q0 + w*16 + lg*4 + r] * 0.125f;

    // ---------------- phase A: rowsums ----------------
    float rs[4] = {0.f, 0.f, 0.f, 0.f};
    for (int k0 = 0; k0 < SEQ; k0 += 64) {
        if (k0) __syncthreads();
#pragma unroll
        for (int r = 0; r < 2; ++r) {
            int s = r*256 + t; int kr = s >> 3, cb = (s & 7) * 16;
            size_t g = (rbase + k0 + kr) * DEPTH + (s & 7) * 8;
            *(short8v*)((char*)KhS + SWZ(kr, cb)) = *(const short8v*)&LKh[g];
            *(short8v*)((char*)KlS + SWZ(kr, cb)) = *(const short8v*)&LKl[g];
        }
        __syncthreads();

        f32x4 acc[4];
#pragma unroll
        for (int f = 0; f < 4; ++f) acc[f] = (f32x4){0.f,0.f,0.f,0.f};
        __builtin_amdgcn_s_setprio(1);
#pragma unroll
        for (int f = 0; f < 4; ++f)
#pragma unroll
            for (int d = 0; d < 2; ++d) {
                int off = SWZ(f*16 + lr, d*64 + lg*16);
                short8v kbh = *(const short8v*)((const char*)KhS + off);
                short8v kbl = *(const short8v*)((const char*)KlS + off);
                acc[f] = __builtin_amdgcn_mfma_f32_16x16x32_bf16(qh[d], kbh, acc[f], 0, 0, 0);
                acc[f] = __builtin_amdgcn_mfma_f32_16x16x32_bf16(qh[d], kbl, acc[f], 0, 0, 0);
                acc[f] = __builtin_amdgcn_mfma_f32_16x16x32_bf16(ql[d], kbh, acc[f], 0, 0, 0);
            }
        __builtin_amdgcn_s_setprio(0);
#pragma unroll
        for (int f = 0; f < 4; ++f)
#pragma unroll
            for (int r = 0; r < 4; ++r)
                rs[r] += fast_csch(fmaf(acc[f][r], -0.125f, e8[r]));
    }
#pragma unroll
    for (int m = 1; m < 16; m <<= 1)
#pragma unroll
        for (int r = 0; r < 4; ++r) rs[r] += __shfl_xor(rs[r], m, 16);
    float inv[4];
#pragma unroll
    for (int r = 0; r < 4; ++r) inv[r] = 1.0f / rs[r];

    // ---------------- phase B: normalized write + PV ----------------
    f32x4 av[4];
#pragma unroll
    for (int nf = 0; nf < 4; ++nf) av[nf] = (f32x4){0.f,0.f,0.f,0.f};

    for (int k0 = 0; k0 < SEQ; k0 += 64) {
        __syncthreads();
#pragma unroll
        for (int r = 0; r < 2; ++r) {
            int s = r*256 + t; int kr = s >> 3, cb = (s & 7) * 16;
            size_t g = (rbase + k0 + kr) * DEPTH + (s & 7) * 8;
            *(short8v*)((char*)KhS + SWZ(kr, cb)) = *(const short8v*)&LKh[g];
            *(short8v*)((char*)KlS + SWZ(kr, cb)) = *(const short8v*)&LKl[g];
        }
#pragma unroll
        for (int r = 0; r < 2; ++r) {
            int s = r*256 + t; int dd = s >> 3, cb = (s & 7) * 16;
            *(short8v*)((char*)VtS + SWZ(dd, cb)) =
                *(const short8v*)&VT[((size_t)bh * DEPTH + dd) * SEQ + k0 + (s & 7) * 8];
        }
        __syncthreads();

        f32x4 acc[4];
#pragma unroll
        for (int f = 0; f < 4; ++f) acc[f] = (f32x4){0.f,0.f,0.f,0.f};
        __builtin_amdgcn_s_setprio(1);
#pragma unroll
        for (int f = 0; f < 4; ++f)
#pragma unroll
            for (int d = 0; d < 2; ++d) {
                int off = SWZ(f*16 + lr, d*64 + lg*16);
                short8v kbh = *(const short8v*)((const char*)KhS + off);
                short8v kbl = *(const short8v*)((const char*)KlS + off);
                acc[f] = __builtin_amdgcn_mfma_f32_16x16x32_bf16(qh[d], kbh, acc[f], 0, 0, 0);
                acc[f] = __builtin_amdgcn_mfma_f32_16x16x32_bf16(qh[d], kbl, acc[f], 0, 0, 0);
                acc[f] = __builtin_amdgcn_mfma_f32_16x16x32_bf16(ql[d], kbh, acc[f], 0, 0, 0);
            }
        __builtin_amdgcn_s_setprio(0);

        // csch + normalized ATTN write + PS (own-wave rows; no barrier needed)
#pragma unroll
        for (int f = 0; f < 4; ++f)
#pragma unroll
            for (int r = 0; r < 4; ++r) {
                float c = fast_csch(fmaf(acc[f][r], -0.125f, e8[r]));
                float a = c * inv[r];
                int q = w*16 + lg*4 + r;
                ATTN[(rbase + q0 + q) * SEQ + k0 + f*16 + lr] = a;
                *(u16*)((char*)PS + SWZ(q, (f*16 + lr)*2)) = f2bf(a);
            }

        short8v pa[2];
#pragma unroll
        for (int ks = 0; ks < 2; ++ks)
            pa[ks] = *(const short8v*)((const char*)PS + SWZ(w*16 + lr, ks*64 + lg*16));
        __builtin_amdgcn_s_setprio(1);
#pragma unroll
        for (int nf = 0; nf < 4; ++nf)
#pragma unroll
            for (int ks = 0; ks < 2; ++ks) {
                short8v vb = *(const short8v*)((const char*)VtS + SWZ(nf*16 + lr, ks*64 + lg*16));
                av[nf] = __builtin_amdgcn_mfma_f32_16x16x32_bf16(pa[ks], vb, av[nf], 0, 0, 0);
            }
        __builtin_amdgcn_s_setprio(0);
    }

    // OV write: normalized, (B,S,DM) layout, split bf16
    const int b = bh >> 4, h = bh & (NH - 1);
#pragma unroll
    for (int nf = 0; nf < 4; ++nf)
#pragma unroll
        for (int r = 0; r < 4; ++r) {
            int q = w*16 + lg*4 + r;
            int d = nf*16 + lr;
            size_t o = ((size_t)(b * SEQ + q0 + q)) * DM + h * DEPTH + d;
            float v = av[nf][r];
            u16 hh = f2bf(v);
            OH[o] = hh;
            OL[o] = f2bf(v - bf2f(hh));
        }
}

// ---------------------------------------------------------------------------
extern "C" void kernel_launch(void* const* d_in, const int* in_sizes, int n_in,
                              void* d_out, int out_size, void* d_ws, size_t ws_size,
                              hipStream_t stream)
{
    const float* q_in = (const float*)d_in[0];
    const float* k_in = (const float*)d_in[1];
    const float* Wq = (const float*)d_in[2];
    const float* bq = (const float*)d_in[3];
    const float* Wk = (const float*)d_in[4];
    const float* bk = (const float*)d_in[5];
    const float* Wv = (const float*)d_in[6];
    const float* bvp = (const float*)d_in[7];
    const float* Wo = (const float*)d_in[8];
    const float* bo = (const float*)d_in[9];
    const float* g1 = (const float*)d_in[10];
    const float* b1 = (const float*)d_in[11];
    const float* g2 = (const float*)d_in[12];
    const float* b2 = (const float*)d_in[13];
    const float* g3 = (const float*)d_in[14];
    const float* b3 = (const float*)d_in[15];

    float* out0 = (float*)d_out;                     // (B,S,DM)
    float* attn = out0 + (size_t)ROWS * DM;          // (B,H,S,S)

    char* base = (char*)d_ws;
    const size_t SLOT = (size_t)ROWS * DM * 4;       // 16 MB
    const size_t HALF = (size_t)ROWS * DM;           // 4M u16 elements
    float* S0f = (float*)(base);
    float* S1f = (float*)(base + SLOT);
    float* S2f = (float*)(base + 2*SLOT);
    float* S3f = (float*)(base + 3*SLOT);
    u16* S0h = (u16*)S0f;
    u16* S3h = (u16*)S3f; u16* S3l = S3h + HALF;
    // attention operand views
    u16* QPh = (u16*)S3f; u16* QPl = QPh + HALF;
    u16* LKh = (u16*)S2f; u16* LKl = LKh + HALF;
    u16* Vb  = (u16*)S0f; u16* VTp = Vb + HALF;
    u16* OHp = (u16*)S1f; u16* OLp = OHp + HALF;
    // non-transposed Wq split (temporary, lives in S0 before k2 is produced)
    u16* WqnH = S0h;
    u16* WqnL = S0h + (size_t)DM*DM;

    char* wbase = base + 4*SLOT;
    const size_t WSZ = (size_t)DM * DM * 2;          // 2 MB per bf16 matrix
    u16* WqH = (u16*)(wbase);           u16* WqL = (u16*)(wbase + WSZ);
    u16* WkH = (u16*)(wbase + 2*WSZ);   u16* WkL = (u16*)(wbase + 3*WSZ);
    u16* WvH = (u16*)(wbase + 4*WSZ);   u16* WvL = (u16*)(wbase + 5*WSZ);
    u16* WoH = (u16*)(wbase + 6*WSZ);   u16* WoL = (u16*)(wbase + 7*WSZ);
    u16* W2H = (u16*)(wbase + 8*WSZ);   u16* W2L = (u16*)(wbase + 9*WSZ);
    float* ent = (float*)(wbase + 10*WSZ);
    float* bq2 = ent + BHS;

    const dim3 ggrid(DM/64, ROWS/128);               // (16, 32)
    const dim3 g2grid(DM/64, DM/128);                // (16, 8)

    // all weight prep in one launch (4 transposes + Wq split + bias2)
    wprep_kernel<<<dim3(32,32,6), 256, 0, stream>>>(
        Wq, Wk, Wv, Wo, bq,
        WqH, WqL, WkH, WkL, WvH, WvL, WoH, WoL, WqnH, WqnL, bq2);
    // W2^T = Wq^T @ Wq^T  (A = WqT split, B = Wq non-transposed split)
    gemm_mfma<1><<<g2grid, 256, 0, stream>>>(WqH, WqL, WqnH, WqnL, nullptr,
                                             nullptr, W2H, W2L);

    // q2 = q_in @ W2 + bq2 (fp32 -> S2f)
    gemm_f32a<0><<<ggrid, 256, 0, stream>>>(q_in, W2H, W2L, bq2, S2f, nullptr, nullptr);
    // k1 = k_in @ Wk + bk (split -> S3)
    gemm_f32a<1><<<ggrid, 256, 0, stream>>>(k_in, WkH, WkL, bk, nullptr, S3h, S3l);
    // k2 = k1 @ Wk + bk (fp32 -> S0f) ; v = k1 @ Wv + bv (fp32 -> S1f)
    gemm_mfma<0><<<ggrid, 256, 0, stream>>>(S3h, S3l, WkH, WkL, bk, S0f, nullptr, nullptr);
    gemm_mfma<0><<<ggrid, 256, 0, stream>>>(S3h, S3l, WvH, WvL, bvp, S1f, nullptr, nullptr);

    // LN + head softmax -> bf16 BHSD operands
    ln_head_kernel<0><<<ROWS, 256, 0, stream>>>(S2f, g1, b1, QPh, QPl, ent);
    ln_head_kernel<1><<<ROWS, 256, 0, stream>>>(S0f, g2, b2, LKh, LKl, nullptr);
    ln_head_kernel<2><<<ROWS, 256, 0, stream>>>(S1f, g3, b3, Vb, nullptr, nullptr);
    vtrans_kernel<<<dim3(SEQ/256, BS*NH), 256, 0, stream>>>(Vb, VTp);

    // fused attention (normalized attn + normalized split OV)
    attn5_kernel<<<dim3(SEQ/64 * BS*NH), 256, 0, stream>>>(
        QPh, QPl, LKh, LKl, VTp, ent, attn, OHp, OLp);

    // final projection
    gemm_mfma<0><<<ggrid, 256, 0, stream>>>(OHp, OLp, WoH, WoL, bo, out0, nullptr, nullptr);
}

// Round 9
// 500.154 us; speedup vs baseline: 1.2099x; 1.1469x over previous
//
#include <hip/hip_runtime.h>
#include <cstddef>
#include <cstdint>

#define BS      2
#define SEQ     2048
#define DM      1024
#define NH      16
#define DEPTH   64
#define ROWS    (BS*SEQ)          // 4096
#define BHS     (BS*NH*SEQ)       // 65536

typedef unsigned short u16;
typedef __attribute__((ext_vector_type(8))) short short8v;
typedef __attribute__((ext_vector_type(4))) float f32x4;

// swizzled byte offset into a [64 rows][128 B] LDS tile (T2 / G4 fix)
#define SWZ(row, cb) ((((row) << 7)) | ((cb) ^ (((row) & 7) << 4)))

__device__ __forceinline__ u16 f2bf(float x) {
    unsigned u = __builtin_bit_cast(unsigned, x);
    unsigned r = u + 0x7FFFu + ((u >> 16) & 1u);
    return (u16)(r >> 16);
}
__device__ __forceinline__ float bf2f(u16 h) {
    unsigned u = ((unsigned)h) << 16;
    return __builtin_bit_cast(float, u);
}

// fast csch(x)=1/sinh(x): big path 2t/(t^2-1), t=e^x; small |x|<0.04: 1/x - x/6.
__device__ __forceinline__ float fast_csch(float x) {
    float t    = __expf(x);
    float den  = fmaf(t, t, -1.0f);
    bool  sm   = fabsf(x) < 0.04f;
    float d    = sm ? x : den;
    float r    = __builtin_amdgcn_rcpf(d);
    float big  = 2.0f * t * r;
    float smal = fmaf(x, -(1.0f/6.0f), r);
    return sm ? smal : big;
}

// ---------------------------------------------------------------------------
// All weight prep in ONE launch (z = 0..5):
//  z<4 : transpose+split W[z] -> [N][K] bf16 hi/lo
//  z=4 : elementwise split of Wq (non-transposed)
//  z=5 : bias2[n] = bq[n] + sum_k bq[k]*Wq[k][n]
// ---------------------------------------------------------------------------
__global__ __launch_bounds__(256) void wprep_kernel(
    const float* __restrict__ W0, const float* __restrict__ W1,
    const float* __restrict__ W2_, const float* __restrict__ W3,
    const float* __restrict__ bq,
    u16* __restrict__ H0, u16* __restrict__ L0, u16* __restrict__ H1, u16* __restrict__ L1,
    u16* __restrict__ H2, u16* __restrict__ L2, u16* __restrict__ H3, u16* __restrict__ L3,
    u16* __restrict__ HN, u16* __restrict__ LN_, float* __restrict__ bq2)
{
    const int z = blockIdx.z;
    if (z == 4) {
        int bid = blockIdx.y * 32 + blockIdx.x;
        int i = bid * 256 + threadIdx.x;           // float4 index over DM*DM/4
        float4 v = ((const float4*)W0)[i];
        u16 h0 = f2bf(v.x), h1 = f2bf(v.y), h2 = f2bf(v.z), h3 = f2bf(v.w);
        u16 l0 = f2bf(v.x - bf2f(h0)), l1 = f2bf(v.y - bf2f(h1));
        u16 l2 = f2bf(v.z - bf2f(h2)), l3 = f2bf(v.w - bf2f(h3));
        uint2 hh, ll;
        hh.x = (unsigned)h0 | ((unsigned)h1 << 16); hh.y = (unsigned)h2 | ((unsigned)h3 << 16);
        ll.x = (unsigned)l0 | ((unsigned)l1 << 16); ll.y = (unsigned)l2 | ((unsigned)l3 << 16);
        ((uint2*)HN)[i] = hh;
        ((uint2*)LN_)[i] = ll;
        return;
    }
    if (z == 5) {
        if (blockIdx.y != 0 || blockIdx.x >= 16) return;
        __shared__ float part[4][64];
        const int t = threadIdx.x;
        const int nl = t & 63, kk = t >> 6;
        const int n = blockIdx.x * 64 + nl;
        float acc = 0.0f;
#pragma unroll 8
        for (int k = kk*256; k < kk*256 + 256; ++k)
            acc = fmaf(bq[k], W0[(size_t)k * DM + n], acc);
        part[kk][nl] = acc;
        __syncthreads();
        if (t < 64)
            bq2[blockIdx.x*64 + t] = part[0][t] + part[1][t] + part[2][t] + part[3][t]
                                   + bq[blockIdx.x*64 + t];
        return;
    }
    const float* W; u16* H; u16* L;
    switch (z) {
        case 0: W = W0; H = H0; L = L0; break;
        case 1: W = W1; H = H1; L = L1; break;
        case 2: W = W2_; H = H2; L = L2; break;
        default: W = W3; H = H3; L = L3; break;
    }
    __shared__ float tile[32][33];
    const int bn = blockIdx.x, bk = blockIdx.y;
    const int c = threadIdx.x & 31, r0 = threadIdx.x >> 5;
#pragma unroll
    for (int r = 0; r < 32; r += 8)
        tile[r0 + r][c] = W[(size_t)(bk*32 + r0 + r) * DM + bn*32 + c];
    __syncthreads();
#pragma unroll
    for (int r = 0; r < 32; r += 8) {
        float v = tile[c][r0 + r];
        u16 h = f2bf(v);
        size_t o = (size_t)(bn*32 + r0 + r) * DM + bk*32 + c;
        H[o] = h;
        L[o] = f2bf(v - bf2f(h));
    }
}

// ---------------------------------------------------------------------------
// Split-bf16 MFMA GEMM: C = A@W (+ bias). A split bf16 [M][K]; B split [N][K].
// ---------------------------------------------------------------------------
template<int OUT_MODE>
__global__ __launch_bounds__(256) void gemm_mfma(
    const u16* __restrict__ Ah, const u16* __restrict__ Al,
    const u16* __restrict__ Bh, const u16* __restrict__ Bl,
    const float* __restrict__ bias, float* __restrict__ C,
    u16* __restrict__ Ch, u16* __restrict__ Cl)
{
    constexpr int K = 1024, N = 1024;
    __shared__ u16 AsH[128*40], AsL[128*40], BsH[64*40], BsL[64*40];

    const int t = threadIdx.x;
    const int m0 = blockIdx.y * 128;
    const int n0 = blockIdx.x * 64;
    const int lane = t & 63, w = t >> 6;
    const int wr = w >> 1, wc = w & 1;
    const int lr = lane & 15, lk = lane >> 4;

    f32x4 acc[4][2];
#pragma unroll
    for (int i = 0; i < 4; ++i)
#pragma unroll
        for (int j = 0; j < 2; ++j) acc[i][j] = (f32x4){0.f,0.f,0.f,0.f};

    for (int k0 = 0; k0 < K; k0 += 32) {
        __syncthreads();
#pragma unroll
        for (int r = 0; r < 2; ++r) {
            int s = r*256 + t;
            int row = s >> 2, c = s & 3;
            size_t g = (size_t)(m0 + row) * K + k0 + c*8;
            *(short8v*)&AsH[row*40 + c*8] = *(const short8v*)&Ah[g];
            *(short8v*)&AsL[row*40 + c*8] = *(const short8v*)&Al[g];
        }
        {
            int row = t >> 2, c = t & 3;
            size_t g = (size_t)(n0 + row) * K + k0 + c*8;
            *(short8v*)&BsH[row*40 + c*8] = *(const short8v*)&Bh[g];
            *(short8v*)&BsL[row*40 + c*8] = *(const short8v*)&Bl[g];
        }
        __syncthreads();

        short8v ah[4], al[4], bh[2], bl[2];
#pragma unroll
        for (int i = 0; i < 4; ++i) {
            int off = (wr*64 + i*16 + lr)*40 + lk*8;
            ah[i] = *(const short8v*)&AsH[off];
            al[i] = *(const short8v*)&AsL[off];
        }
#pragma unroll
        for (int j = 0; j < 2; ++j) {
            int off = (wc*32 + j*16 + lr)*40 + lk*8;
            bh[j] = *(const short8v*)&BsH[off];
            bl[j] = *(const short8v*)&BsL[off];
        }
        __builtin_amdgcn_s_setprio(1);
#pragma unroll
        for (int i = 0; i < 4; ++i)
#pragma unroll
            for (int j = 0; j < 2; ++j) {
                acc[i][j] = __builtin_amdgcn_mfma_f32_16x16x32_bf16(ah[i], bh[j], acc[i][j], 0, 0, 0);
                acc[i][j] = __builtin_amdgcn_mfma_f32_16x16x32_bf16(ah[i], bl[j], acc[i][j], 0, 0, 0);
                acc[i][j] = __builtin_amdgcn_mfma_f32_16x16x32_bf16(al[i], bh[j], acc[i][j], 0, 0, 0);
            }
        __builtin_amdgcn_s_setprio(0);
    }

    float bj[2];
#pragma unroll
    for (int j = 0; j < 2; ++j) bj[j] = bias ? bias[n0 + wc*32 + j*16 + lr] : 0.0f;
#pragma unroll
    for (int i = 0; i < 4; ++i)
#pragma unroll
        for (int j = 0; j < 2; ++j) {
            int col = n0 + wc*32 + j*16 + lr;
#pragma unroll
            for (int r = 0; r < 4; ++r) {
                int row = m0 + wr*64 + i*16 + lk*4 + r;
                float v = acc[i][j][r] + bj[j];
                size_t o = (size_t)row * N + col;
                if constexpr (OUT_MODE == 0) {
                    C[o] = v;
                } else {
                    u16 h = f2bf(v);
                    Ch[o] = h;
                    Cl[o] = f2bf(v - bf2f(h));
                }
            }
        }
}

// ---------------------------------------------------------------------------
// Dual-B GEMM: C0 = A@B0 + bias0, C1 = A@B1 + bias1 (fp32 out), shared A tile.
// ---------------------------------------------------------------------------
__global__ __launch_bounds__(256) void gemm_dual(
    const u16* __restrict__ Ah, const u16* __restrict__ Al,
    const u16* __restrict__ B0h, const u16* __restrict__ B0l,
    const u16* __restrict__ B1h, const u16* __restrict__ B1l,
    const float* __restrict__ bias0, const float* __restrict__ bias1,
    float* __restrict__ C0, float* __restrict__ C1)
{
    constexpr int K = 1024, N = 1024;
    __shared__ u16 AsH[128*40], AsL[128*40];
    __shared__ u16 B0H[64*40], B0L[64*40], B1H[64*40], B1L[64*40];

    const int t = threadIdx.x;
    const int m0 = blockIdx.y * 128;
    const int n0 = blockIdx.x * 64;
    const int lane = t & 63, w = t >> 6;
    const int wr = w >> 1, wc = w & 1;
    const int lr = lane & 15, lk = lane >> 4;

    f32x4 acc0[4][2], acc1[4][2];
#pragma unroll
    for (int i = 0; i < 4; ++i)
#pragma unroll
        for (int j = 0; j < 2; ++j) {
            acc0[i][j] = (f32x4){0.f,0.f,0.f,0.f};
            acc1[i][j] = (f32x4){0.f,0.f,0.f,0.f};
        }

    for (int k0 = 0; k0 < K; k0 += 32) {
        __syncthreads();
#pragma unroll
        for (int r = 0; r < 2; ++r) {
            int s = r*256 + t;
            int row = s >> 2, c = s & 3;
            size_t g = (size_t)(m0 + row) * K + k0 + c*8;
            *(short8v*)&AsH[row*40 + c*8] = *(const short8v*)&Ah[g];
            *(short8v*)&AsL[row*40 + c*8] = *(const short8v*)&Al[g];
        }
        {
            int row = t >> 2, c = t & 3;
            size_t g = (size_t)(n0 + row) * K + k0 + c*8;
            *(short8v*)&B0H[row*40 + c*8] = *(const short8v*)&B0h[g];
            *(short8v*)&B0L[row*40 + c*8] = *(const short8v*)&B0l[g];
            *(short8v*)&B1H[row*40 + c*8] = *(const short8v*)&B1h[g];
            *(short8v*)&B1L[row*40 + c*8] = *(const short8v*)&B1l[g];
        }
        __syncthreads();

        short8v ah[4], al[4];
#pragma unroll
        for (int i = 0; i < 4; ++i) {
            int off = (wr*64 + i*16 + lr)*40 + lk*8;
            ah[i] = *(const short8v*)&AsH[off];
            al[i] = *(const short8v*)&AsL[off];
        }
#pragma unroll
        for (int j = 0; j < 2; ++j) {
            int off = (wc*32 + j*16 + lr)*40 + lk*8;
            short8v b0h = *(const short8v*)&B0H[off];
            short8v b0l = *(const short8v*)&B0L[off];
            short8v b1h = *(const short8v*)&B1H[off];
            short8v b1l = *(const short8v*)&B1L[off];
            __builtin_amdgcn_s_setprio(1);
#pragma unroll
            for (int i = 0; i < 4; ++i) {
                acc0[i][j] = __builtin_amdgcn_mfma_f32_16x16x32_bf16(ah[i], b0h, acc0[i][j], 0, 0, 0);
                acc0[i][j] = __builtin_amdgcn_mfma_f32_16x16x32_bf16(ah[i], b0l, acc0[i][j], 0, 0, 0);
                acc0[i][j] = __builtin_amdgcn_mfma_f32_16x16x32_bf16(al[i], b0h, acc0[i][j], 0, 0, 0);
                acc1[i][j] = __builtin_amdgcn_mfma_f32_16x16x32_bf16(ah[i], b1h, acc1[i][j], 0, 0, 0);
                acc1[i][j] = __builtin_amdgcn_mfma_f32_16x16x32_bf16(ah[i], b1l, acc1[i][j], 0, 0, 0);
                acc1[i][j] = __builtin_amdgcn_mfma_f32_16x16x32_bf16(al[i], b1h, acc1[i][j], 0, 0, 0);
            }
            __builtin_amdgcn_s_setprio(0);
        }
    }

    float bj0[2], bj1[2];
#pragma unroll
    for (int j = 0; j < 2; ++j) {
        bj0[j] = bias0[n0 + wc*32 + j*16 + lr];
        bj1[j] = bias1[n0 + wc*32 + j*16 + lr];
    }
#pragma unroll
    for (int i = 0; i < 4; ++i)
#pragma unroll
        for (int j = 0; j < 2; ++j) {
            int col = n0 + wc*32 + j*16 + lr;
#pragma unroll
            for (int r = 0; r < 4; ++r) {
                int row = m0 + wr*64 + i*16 + lk*4 + r;
                size_t o = (size_t)row * N + col;
                C0[o] = acc0[i][j][r] + bj0[j];
                C1[o] = acc1[i][j][r] + bj1[j];
            }
        }
}

// ---------------------------------------------------------------------------
// GEMM with fp32 A input (split performed during LDS staging). B split [N][K].
// ---------------------------------------------------------------------------
template<int OUT_MODE>
__global__ __launch_bounds__(256) void gemm_f32a(
    const float* __restrict__ A,
    const u16* __restrict__ Bh, const u16* __restrict__ Bl,
    const float* __restrict__ bias, float* __restrict__ C,
    u16* __restrict__ Ch, u16* __restrict__ Cl)
{
    constexpr int K = 1024, N = 1024;
    __shared__ u16 AsH[128*40], AsL[128*40], BsH[64*40], BsL[64*40];

    const int t = threadIdx.x;
    const int m0 = blockIdx.y * 128;
    const int n0 = blockIdx.x * 64;
    const int lane = t & 63, w = t >> 6;
    const int wr = w >> 1, wc = w & 1;
    const int lr = lane & 15, lk = lane >> 4;

    f32x4 acc[4][2];
#pragma unroll
    for (int i = 0; i < 4; ++i)
#pragma unroll
        for (int j = 0; j < 2; ++j) acc[i][j] = (f32x4){0.f,0.f,0.f,0.f};

    for (int k0 = 0; k0 < K; k0 += 32) {
        __syncthreads();
#pragma unroll
        for (int r = 0; r < 2; ++r) {
            int j = r*256 + t;               // 0..511 groups of 8 floats
            int row = j >> 2, c8 = j & 3;
            const float* src = &A[(size_t)(m0 + row) * K + k0 + c8*8];
            float4 a = *(const float4*)src;
            float4 b = *(const float4*)(src + 4);
            float xs[8] = {a.x,a.y,a.z,a.w,b.x,b.y,b.z,b.w};
            short8v hv, lv;
#pragma unroll
            for (int jj = 0; jj < 8; ++jj) {
                u16 h = f2bf(xs[jj]);
                hv[jj] = (short)h;
                lv[jj] = (short)f2bf(xs[jj] - bf2f(h));
            }
            *(short8v*)&AsH[row*40 + c8*8] = hv;
            *(short8v*)&AsL[row*40 + c8*8] = lv;
        }
        {
            int row = t >> 2, c = t & 3;
            size_t g = (size_t)(n0 + row) * K + k0 + c*8;
            *(short8v*)&BsH[row*40 + c*8] = *(const short8v*)&Bh[g];
            *(short8v*)&BsL[row*40 + c*8] = *(const short8v*)&Bl[g];
        }
        __syncthreads();

        short8v ah[4], al[4], bh[2], bl[2];
#pragma unroll
        for (int i = 0; i < 4; ++i) {
            int off = (wr*64 + i*16 + lr)*40 + lk*8;
            ah[i] = *(const short8v*)&AsH[off];
            al[i] = *(const short8v*)&AsL[off];
        }
#pragma unroll
        for (int j = 0; j < 2; ++j) {
            int off = (wc*32 + j*16 + lr)*40 + lk*8;
            bh[j] = *(const short8v*)&BsH[off];
            bl[j] = *(const short8v*)&BsL[off];
        }
        __builtin_amdgcn_s_setprio(1);
#pragma unroll
        for (int i = 0; i < 4; ++i)
#pragma unroll
            for (int j = 0; j < 2; ++j) {
                acc[i][j] = __builtin_amdgcn_mfma_f32_16x16x32_bf16(ah[i], bh[j], acc[i][j], 0, 0, 0);
                acc[i][j] = __builtin_amdgcn_mfma_f32_16x16x32_bf16(ah[i], bl[j], acc[i][j], 0, 0, 0);
                acc[i][j] = __builtin_amdgcn_mfma_f32_16x16x32_bf16(al[i], bh[j], acc[i][j], 0, 0, 0);
            }
        __builtin_amdgcn_s_setprio(0);
    }

    float bj[2];
#pragma unroll
    for (int j = 0; j < 2; ++j) bj[j] = bias ? bias[n0 + wc*32 + j*16 + lr] : 0.0f;
#pragma unroll
    for (int i = 0; i < 4; ++i)
#pragma unroll
        for (int j = 0; j < 2; ++j) {
            int col = n0 + wc*32 + j*16 + lr;
#pragma unroll
            for (int r = 0; r < 4; ++r) {
                int row = m0 + wr*64 + i*16 + lk*4 + r;
                float v = acc[i][j][r] + bj[j];
                size_t o = (size_t)row * N + col;
                if constexpr (OUT_MODE == 0) {
                    C[o] = v;
                } else {
                    u16 h = f2bf(v);
                    Ch[o] = h;
                    Cl[o] = f2bf(v - bf2f(h));
                }
            }
        }
}

// ---------------------------------------------------------------------------
// Fused LayerNorm -> per-head softmax, all 3 streams in one launch.
// blockIdx.y: 0 = q_prob hi/lo + ENT ; 1 = log(prob+eps) hi/lo ; 2 = LN bf16.
// ---------------------------------------------------------------------------
__global__ __launch_bounds__(256) void ln3_kernel(
    const float* __restrict__ X0, const float* __restrict__ X1,
    const float* __restrict__ X2,
    const float* __restrict__ G0, const float* __restrict__ B0,
    const float* __restrict__ G1, const float* __restrict__ B1,
    const float* __restrict__ G2, const float* __restrict__ B2,
    u16* __restrict__ QA, u16* __restrict__ QB,
    u16* __restrict__ KA, u16* __restrict__ KB,
    u16* __restrict__ VA, float* __restrict__ ENT)
{
    const int mode = blockIdx.y;
    const float* X; const float* G; const float* Bt;
    if (mode == 0)      { X = X0; G = G0; Bt = B0; }
    else if (mode == 1) { X = X1; G = G1; Bt = B1; }
    else                { X = X2; G = G2; Bt = B2; }

    const int row = blockIdx.x;
    const int tid = threadIdx.x;
    const float* x = X + (size_t)row * DM;
    float4 v = *(const float4*)&x[tid*4];

    float s  = v.x + v.y + v.z + v.w;
    float ss = v.x*v.x + v.y*v.y + v.z*v.z + v.w*v.w;
#pragma unroll
    for (int m = 1; m < 64; m <<= 1) { s += __shfl_xor(s, m); ss += __shfl_xor(ss, m); }
    __shared__ float redS[4], redQ[4];
    const int wave = tid >> 6, lane = tid & 63;
    if (lane == 0) { redS[wave] = s; redQ[wave] = ss; }
    __syncthreads();
    s  = redS[0] + redS[1] + redS[2] + redS[3];
    ss = redQ[0] + redQ[1] + redQ[2] + redQ[3];
    const float mu   = s * (1.0f / DM);
    const float var  = ss * (1.0f / DM) - mu * mu;
    const float rsig = rsqrtf(var + 1e-6f);

    float4 gv = *(const float4*)&G[tid*4];
    float4 bv = *(const float4*)&Bt[tid*4];
    float y0 = (v.x - mu) * rsig * gv.x + bv.x;
    float y1 = (v.y - mu) * rsig * gv.y + bv.y;
    float y2 = (v.z - mu) * rsig * gv.z + bv.z;
    float y3 = (v.w - mu) * rsig * gv.w + bv.w;

    const int b  = row >> 11;
    const int sl = row & (SEQ - 1);
    const int h  = tid >> 4;
    const size_t obase = (((size_t)(b*NH + h)) * SEQ + sl) * DEPTH + (tid & 15) * 4;

    if (mode == 2) {
        unsigned w0 = (unsigned)f2bf(y0) | ((unsigned)f2bf(y1) << 16);
        unsigned w1 = (unsigned)f2bf(y2) | ((unsigned)f2bf(y3) << 16);
        *(uint2*)&VA[obase] = make_uint2(w0, w1);
        return;
    }

    float mx = fmaxf(fmaxf(y0, y1), fmaxf(y2, y3));
#pragma unroll
    for (int m = 1; m < 16; m <<= 1) mx = fmaxf(mx, __shfl_xor(mx, m, 16));
    float e0 = expf(y0 - mx), e1 = expf(y1 - mx), e2 = expf(y2 - mx), e3 = expf(y3 - mx);
    float se = e0 + e1 + e2 + e3;
#pragma unroll
    for (int m = 1; m < 16; m <<= 1) se += __shfl_xor(se, m, 16);
    float inv = 1.0f / se;
    float p0 = e0*inv, p1 = e1*inv, p2 = e2*inv, p3 = e3*inv;
    float o0, o1, o2, o3;
    u16* OA; u16* OB;
    if (mode == 0) { o0 = p0; o1 = p1; o2 = p2; o3 = p3; OA = QA; OB = QB; }
    else {
        o0 = logf(p0 + 2e-8f); o1 = logf(p1 + 2e-8f);
        o2 = logf(p2 + 2e-8f); o3 = logf(p3 + 2e-8f);
        OA = KA; OB = KB;
    }
    u16 h0 = f2bf(o0), h1 = f2bf(o1), h2 = f2bf(o2), h3 = f2bf(o3);
    unsigned w0 = (unsigned)h0 | ((unsigned)h1 << 16);
    unsigned w1 = (unsigned)h2 | ((unsigned)h3 << 16);
    *(uint2*)&OA[obase] = make_uint2(w0, w1);
    u16 l0 = f2bf(o0 - bf2f(h0)), l1 = f2bf(o1 - bf2f(h1));
    u16 l2 = f2bf(o2 - bf2f(h2)), l3 = f2bf(o3 - bf2f(h3));
    w0 = (unsigned)l0 | ((unsigned)l1 << 16);
    w1 = (unsigned)l2 | ((unsigned)l3 << 16);
    *(uint2*)&OB[obase] = make_uint2(w0, w1);

    if (mode == 0) {
        float lse = logf(se);
        float el = p0*(y0-mx-lse) + p1*(y1-mx-lse) + p2*(y2-mx-lse) + p3*(y3-mx-lse);
#pragma unroll
        for (int m = 1; m < 16; m <<= 1) el += __shfl_xor(el, m, 16);
        if ((tid & 15) == 0) ENT[((size_t)(b*NH + h)) * SEQ + sl] = el;
    }
}

// ---------------------------------------------------------------------------
// V transpose via LDS: Vb [bh][s][d] bf16 -> VT [bh][d][s] bf16 (coalesced)
// ---------------------------------------------------------------------------
__global__ __launch_bounds__(256) void vtrans_kernel(
    const u16* __restrict__ Vb, u16* __restrict__ VT)
{
    __shared__ u16 T[256*72];
    const int bh = blockIdx.y;
    const int s0 = blockIdx.x * 256;
    const int t  = threadIdx.x;
#pragma unroll
    for (int i = 0; i < 8; ++i) {
        int c = i*256 + t;
        int s = c >> 3, d0 = (c & 7) * 8;
        *(short8v*)&T[s*72 + d0] =
            *(const short8v*)&Vb[((size_t)bh*SEQ + s0 + s)*DEPTH + d0];
    }
    __syncthreads();
#pragma unroll
    for (int i = 0; i < 8; ++i) {
        int c = i*256 + t;
        int d = c >> 5, sl0 = (c & 31) * 8;
        short8v v;
#pragma unroll
        for (int j = 0; j < 8; ++j) v[j] = (short)T[(sl0 + j)*72 + d];
        *(short8v*)&VT[((size_t)bh*DEPTH + d)*SEQ + s0 + sl0] = v;
    }
}

// ---------------------------------------------------------------------------
// attn7: attn5 + non-temporal ATTN stores (write-around keeps K/V in L2).
// ---------------------------------------------------------------------------
__global__ __launch_bounds__(256, 4) void attn7_kernel(
    const u16* __restrict__ QPh, const u16* __restrict__ QPl,
    const u16* __restrict__ LKh, const u16* __restrict__ LKl,
    const u16* __restrict__ VT, const float* __restrict__ ENT,
    float* __restrict__ ATTN, u16* __restrict__ OH, u16* __restrict__ OL)
{
    const int wg   = blockIdx.x;
    const int wgid = (wg & 7) * 128 + (wg >> 3);
    const int bh   = wgid >> 5;
    const int q0   = (wgid & 31) * 64;

    const int t  = threadIdx.x;
    const int l  = t & 63, w = t >> 6;
    const int lr = l & 15, lg = l >> 4;
    const size_t rbase = (size_t)bh * SEQ;

    __shared__ u16 KhS[64*64], KlS[64*64], VtS[64*64], PS[64*64];

    short8v qh[2], ql[2];
#pragma unroll
    for (int d = 0; d < 2; ++d) {
        size_t g = (rbase + q0 + w*16 + lr) * DEPTH + d*32 + lg*8;
        qh[d] = *(const short8v*)&QPh[g];
        ql[d] = *(const short8v*)&QPl[g];
    }
    float e8[4];
#pragma unroll
    for (int r = 0; r < 4; ++r)
        e8[r] = ENT[rbase + q0 + w*16 + lg*4 + r] * 0.125f;

    // ---------------- phase A: rowsums ----------------
    float rs[4] = {0.f, 0.f, 0.f, 0.f};
    for (int k0 = 0; k0 < SEQ; k0 += 64) {
        if (k0) __syncthreads();
#pragma unroll
        for (int r = 0; r < 2; ++r) {
            int s = r*256 + t; int kr = s >> 3, cb = (s & 7) * 16;
            size_t g = (rbase + k0 + kr) * DEPTH + (s & 7) * 8;
            *(short8v*)((char*)KhS + SWZ(kr, cb)) = *(const short8v*)&LKh[g];
            *(short8v*)((char*)KlS + SWZ(kr, cb)) = *(const short8v*)&LKl[g];
        }
        __syncthreads();

        f32x4 acc[4];
#pragma unroll
        for (int f = 0; f < 4; ++f) acc[f] = (f32x4){0.f,0.f,0.f,0.f};
        __builtin_amdgcn_s_setprio(1);
#pragma unroll
        for (int f = 0; f < 4; ++f)
#pragma unroll
            for (int d = 0; d < 2; ++d) {
                int off = SWZ(f*16 + lr, d*64 + lg*16);
                short8v kbh = *(const short8v*)((const char*)KhS + off);
                short8v kbl = *(const short8v*)((const char*)KlS + off);
                acc[f] = __builtin_amdgcn_mfma_f32_16x16x32_bf16(qh[d], kbh, acc[f], 0, 0, 0);
                acc[f] = __builtin_amdgcn_mfma_f32_16x16x32_bf16(qh[d], kbl, acc[f], 0, 0, 0);
                acc[f] = __builtin_amdgcn_mfma_f32_16x16x32_bf16(ql[d], kbh, acc[f], 0, 0, 0);
            }
        __builtin_amdgcn_s_setprio(0);
#pragma unroll
        for (int f = 0; f < 4; ++f)
#pragma unroll
            for (int r = 0; r < 4; ++r)
                rs[r] += fast_csch(fmaf(acc[f][r], -0.125f, e8[r]));
    }
#pragma unroll
    for (int m = 1; m < 16; m <<= 1)
#pragma unroll
        for (int r = 0; r < 4; ++r) rs[r] += __shfl_xor(rs[r], m, 16);
    float inv[4];
#pragma unroll
    for (int r = 0; r < 4; ++r) inv[r] = 1.0f / rs[r];

    // ---------------- phase B: normalized write + PV ----------------
    f32x4 av[4];
#pragma unroll
    for (int nf = 0; nf < 4; ++nf) av[nf] = (f32x4){0.f,0.f,0.f,0.f};

    for (int k0 = 0; k0 < SEQ; k0 += 64) {
        __syncthreads();
#pragma unroll
        for (int r = 0; r < 2; ++r) {
            int s = r*256 + t; int kr = s >> 3, cb = (s & 7) * 16;
            size_t g = (rbase + k0 + kr) * DEPTH + (s & 7) * 8;
            *(short8v*)((char*)KhS + SWZ(kr, cb)) = *(const short8v*)&LKh[g];
            *(short8v*)((char*)KlS + SWZ(kr, cb)) = *(const short8v*)&LKl[g];
        }
#pragma unroll
        for (int r = 0; r < 2; ++r) {
            int s = r*256 + t; int dd = s >> 3, cb = (s & 7) * 16;
            *(short8v*)((char*)VtS + SWZ(dd, cb)) =
                *(const short8v*)&VT[((size_t)bh * DEPTH + dd) * SEQ + k0 + (s & 7) * 8];
        }
        __syncthreads();

        f32x4 acc[4];
#pragma unroll
        for (int f = 0; f < 4; ++f) acc[f] = (f32x4){0.f,0.f,0.f,0.f};
        __builtin_amdgcn_s_setprio(1);
#pragma unroll
        for (int f = 0; f < 4; ++f)
#pragma unroll
            for (int d = 0; d < 2; ++d) {
                int off = SWZ(f*16 + lr, d*64 + lg*16);
                short8v kbh = *(const short8v*)((const char*)KhS + off);
                short8v kbl = *(const short8v*)((const char*)KlS + off);
                acc[f] = __builtin_amdgcn_mfma_f32_16x16x32_bf16(qh[d], kbh, acc[f], 0, 0, 0);
                acc[f] = __builtin_amdgcn_mfma_f32_16x16x32_bf16(qh[d], kbl, acc[f], 0, 0, 0);
                acc[f] = __builtin_amdgcn_mfma_f32_16x16x32_bf16(ql[d], kbh, acc[f], 0, 0, 0);
            }
        __builtin_amdgcn_s_setprio(0);

        // csch + normalized ATTN write (non-temporal) + PS (own-wave rows)
#pragma unroll
        for (int f = 0; f < 4; ++f)
#pragma unroll
            for (int r = 0; r < 4; ++r) {
                float c = fast_csch(fmaf(acc[f][r], -0.125f, e8[r]));
                float a = c * inv[r];
                int q = w*16 + lg*4 + r;
                __builtin_nontemporal_store(a, &ATTN[(rbase + q0 + q) * SEQ + k0 + f*16 + lr]);
                *(u16*)((char*)PS + SWZ(q, (f*16 + lr)*2)) = f2bf(a);
            }

        short8v pa[2];
#pragma unroll
        for (int ks = 0; ks < 2; ++ks)
            pa[ks] = *(const short8v*)((const char*)PS + SWZ(w*16 + lr, ks*64 + lg*16));
        __builtin_amdgcn_s_setprio(1);
#pragma unroll
        for (int nf = 0; nf < 4; ++nf)
#pragma unroll
            for (int ks = 0; ks < 2; ++ks) {
                short8v vb = *(const short8v*)((const char*)VtS + SWZ(nf*16 + lr, ks*64 + lg*16));
                av[nf] = __builtin_amdgcn_mfma_f32_16x16x32_bf16(pa[ks], vb, av[nf], 0, 0, 0);
            }
        __builtin_amdgcn_s_setprio(0);
    }

    // OV write: normalized, (B,S,DM) layout, split bf16
    const int b = bh >> 4, h = bh & (NH - 1);
#pragma unroll
    for (int nf = 0; nf < 4; ++nf)
#pragma unroll
        for (int r = 0; r < 4; ++r) {
            int q = w*16 + lg*4 + r;
            int d = nf*16 + lr;
            size_t o = ((size_t)(b * SEQ + q0 + q)) * DM + h * DEPTH + d;
            float v = av[nf][r];
            u16 hh = f2bf(v);
            OH[o] = hh;
            OL[o] = f2bf(v - bf2f(hh));
        }
}

// ---------------------------------------------------------------------------
extern "C" void kernel_launch(void* const* d_in, const int* in_sizes, int n_in,
                              void* d_out, int out_size, void* d_ws, size_t ws_size,
                              hipStream_t stream)
{
    const float* q_in = (const float*)d_in[0];
    const float* k_in = (const float*)d_in[1];
    const float* Wq = (const float*)d_in[2];
    const float* bq = (const float*)d_in[3];
    const float* Wk = (const float*)d_in[4];
    const float* bk = (const float*)d_in[5];
    const float* Wv = (const float*)d_in[6];
    const float* bvp = (const float*)d_in[7];
    const float* Wo = (const float*)d_in[8];
    const float* bo = (const float*)d_in[9];
    const float* g1 = (const float*)d_in[10];
    const float* b1 = (const float*)d_in[11];
    const float* g2 = (const float*)d_in[12];
    const float* b2 = (const float*)d_in[13];
    const float* g3 = (const float*)d_in[14];
    const float* b3 = (const float*)d_in[15];

    float* out0 = (float*)d_out;                     // (B,S,DM)
    float* attn = out0 + (size_t)ROWS * DM;          // (B,H,S,S)

    char* base = (char*)d_ws;
    const size_t SLOT = (size_t)ROWS * DM * 4;       // 16 MB
    const size_t HALF = (size_t)ROWS * DM;           // 4M u16 elements
    float* S0f = (float*)(base);
    float* S1f = (float*)(base + SLOT);
    float* S2f = (float*)(base + 2*SLOT);
    float* S3f = (float*)(base + 3*SLOT);
    u16* S0h = (u16*)S0f;
    u16* S3h = (u16*)S3f; u16* S3l = S3h + HALF;
    // attention operand views
    u16* QPh = (u16*)S3f; u16* QPl = QPh + HALF;
    u16* LKh = (u16*)S2f; u16* LKl = LKh + HALF;
    u16* Vb  = (u16*)S0f; u16* VTp = Vb + HALF;
    u16* OHp = (u16*)S1f; u16* OLp = OHp + HALF;
    // non-transposed Wq split (temporary, lives in S0 before k2 is produced)
    u16* WqnH = S0h;
    u16* WqnL = S0h + (size_t)DM*DM;

    char* wbase = base + 4*SLOT;
    const size_t WSZ = (size_t)DM * DM * 2;          // 2 MB per bf16 matrix
    u16* WqH = (u16*)(wbase);           u16* WqL = (u16*)(wbase + WSZ);
    u16* WkH = (u16*)(wbase + 2*WSZ);   u16* WkL = (u16*)(wbase + 3*WSZ);
    u16* WvH = (u16*)(wbase + 4*WSZ);   u16* WvL = (u16*)(wbase + 5*WSZ);
    u16* WoH = (u16*)(wbase + 6*WSZ);   u16* WoL = (u16*)(wbase + 7*WSZ);
    u16* W2H = (u16*)(wbase + 8*WSZ);   u16* W2L = (u16*)(wbase + 9*WSZ);
    float* ent = (float*)(wbase + 10*WSZ);
    float* bq2 = ent + BHS;

    const dim3 ggrid(DM/64, ROWS/128);               // (16, 32)
    const dim3 g2grid(DM/64, DM/128);                // (16, 8)

    // all weight prep in one launch (4 transposes + Wq split + bias2)
    wprep_kernel<<<dim3(32,32,6), 256, 0, stream>>>(
        Wq, Wk, Wv, Wo, bq,
        WqH, WqL, WkH, WkL, WvH, WvL, WoH, WoL, WqnH, WqnL, bq2);
    // W2^T = Wq^T @ Wq^T
    gemm_mfma<1><<<g2grid, 256, 0, stream>>>(WqH, WqL, WqnH, WqnL, nullptr,
                                             nullptr, W2H, W2L);

    // q2 = q_in @ W2 + bq2 (fp32 -> S2f)
    gemm_f32a<0><<<ggrid, 256, 0, stream>>>(q_in, W2H, W2L, bq2, S2f, nullptr, nullptr);
    // k1 = k_in @ Wk + bk (split -> S3)
    gemm_f32a<1><<<ggrid, 256, 0, stream>>>(k_in, WkH, WkL, bk, nullptr, S3h, S3l);
    // k2 = k1@Wk+bk -> S0f  AND  v = k1@Wv+bv -> S1f (shared A staging)
    gemm_dual<<<ggrid, 256, 0, stream>>>(S3h, S3l, WkH, WkL, WvH, WvL,
                                         bk, bvp, S0f, S1f);

    // LN + head softmax, all 3 streams in one launch
    ln3_kernel<<<dim3(ROWS, 3), 256, 0, stream>>>(
        S2f, S0f, S1f, g1, b1, g2, b2, g3, b3,
        QPh, QPl, LKh, LKl, Vb, ent);
    vtrans_kernel<<<dim3(SEQ/256, BS*NH), 256, 0, stream>>>(Vb, VTp);

    // fused attention (normalized attn via nt-stores + normalized split OV)
    attn7_kernel<<<dim3(SEQ/64 * BS*NH), 256, 0, stream>>>(
        QPh, QPl, LKh, LKl, VTp, ent, attn, OHp, OLp);

    // final projection
    gemm_mfma<0><<<ggrid, 256, 0, stream>>>(OHp, OLp, WoH, WoL, bo, out0, nullptr, nullptr);
}